// Round 1
// baseline (699.645 us; speedup 1.0000x reference)
//
#include <hip/hip_runtime.h>
#include <hip/hip_bf16.h>
#include <math.h>

#define N_NODES 50000
#define F_INK   256
#define HEADS   8
#define HID     64
#define HH      512     // HEADS*HID
#define NCLS    16
#define NEDGE   400000
#define NEG_SLOPE 0.2f

typedef __attribute__((ext_vector_type(8))) short short8;
typedef __attribute__((ext_vector_type(4))) float float4v;

__device__ __forceinline__ float bf2f(unsigned short u){
    unsigned int x = ((unsigned int)u) << 16;
    float f; __builtin_memcpy(&f, &x, 4); return f;
}
__device__ __forceinline__ unsigned short f2bf(float f){
    unsigned int x; __builtin_memcpy(&x, &f, 4);
    unsigned int r = x + 0x7FFFu + ((x >> 16) & 1u);   // RNE
    return (unsigned short)(r >> 16);
}
__device__ __forceinline__ float lrelu(float a){ return a > 0.f ? a : NEG_SLOPE * a; }

// ---------------- conversions ----------------
__global__ void cvt_f32_bf16(const float* __restrict__ in, unsigned short* __restrict__ out, int n){
    int i = blockIdx.x * blockDim.x + threadIdx.x;
    int stride = gridDim.x * blockDim.x;
    for (; i < n; i += stride) out[i] = f2bf(in[i]);
}

// W1 [256][512] fp32 -> W1T [512][256] bf16
__global__ void cvt_w1t(const float* __restrict__ W1, unsigned short* __restrict__ W1T){
    int i = blockIdx.x * blockDim.x + threadIdx.x;
    if (i >= F_INK * HH) return;
    int k = i / HH, c = i % HH;
    W1T[c * F_INK + k] = f2bf(W1[i]);
}

// ---------------- CSR build ----------------
__global__ void count_edges(const int* __restrict__ dst, int* __restrict__ counts){
    int e = blockIdx.x * blockDim.x + threadIdx.x;
    if (e < NEDGE) atomicAdd(&counts[dst[e]], 1);
}

__global__ void scan_offsets(const int* __restrict__ counts, int* __restrict__ offsets){
    __shared__ int tsum[1024];
    int t = threadIdx.x;
    const int per = (N_NODES + 1023) / 1024;
    int begin = t * per;
    int end = begin + per; if (end > N_NODES) end = N_NODES;
    int s = 0;
    if (begin < N_NODES) for (int i = begin; i < end; i++) s += counts[i];
    tsum[t] = s; __syncthreads();
    int val = s;
    for (int off = 1; off < 1024; off <<= 1){
        int v2 = (t >= off) ? tsum[t - off] : 0;
        __syncthreads();
        val += v2; tsum[t] = val;
        __syncthreads();
    }
    int run = val - s;
    if (begin < N_NODES) for (int i = begin; i < end; i++){ offsets[i] = run; run += counts[i]; }
    if (t == 0) offsets[N_NODES] = tsum[1023];
}

__global__ void scatter_edges(const int* __restrict__ src, const int* __restrict__ dst,
                              const int* __restrict__ offsets, int* __restrict__ cursor,
                              int* __restrict__ esrc){
    int e = blockIdx.x * blockDim.x + threadIdx.x;
    if (e < NEDGE){
        int d = dst[e];
        int pos = offsets[d] + atomicAdd(&cursor[d], 1);
        esrc[pos] = src[e];
    }
}

// ---------------- GEMM1: h1 = bf16(x) @ bf16(W1), output bf16 [N][512] ----------------
// one wave computes a 16-row tile over all 512 cols; K=256 held in registers.
__global__ __launch_bounds__(256) void gemm1(const unsigned short* __restrict__ xb,
                                             const unsigned short* __restrict__ w1t,
                                             unsigned short* __restrict__ h1b){
    int wave = (blockIdx.x * blockDim.x + threadIdx.x) >> 6;
    int lane = threadIdx.x & 63;
    if (wave >= N_NODES / 16) return;
    int rowbase = wave * 16;
    int lr = lane & 15, lk = lane >> 4;
    short8 a[8];
#pragma unroll
    for (int ks = 0; ks < 8; ks++)
        a[ks] = *(const short8*)(xb + (size_t)(rowbase + lr) * F_INK + ks * 32 + lk * 8);
    for (int ct = 0; ct < 32; ct++){
        float4v acc = {0.f, 0.f, 0.f, 0.f};
#pragma unroll
        for (int ks = 0; ks < 8; ks++){
            short8 b = *(const short8*)(w1t + (size_t)(ct * 16 + lr) * F_INK + ks * 32 + lk * 8);
            acc = __builtin_amdgcn_mfma_f32_16x16x32_bf16(a[ks], b, acc, 0, 0, 0);
        }
#pragma unroll
        for (int r = 0; r < 4; r++)
            h1b[(size_t)(rowbase + lk * 4 + r) * HH + ct * 16 + lr] = f2bf(acc[r]);
    }
}

// ---------------- attention dots: al_src/al_dst [N][8] ----------------
__global__ __launch_bounds__(256) void attn1_dots(const unsigned short* __restrict__ h1b,
        const float* __restrict__ a_src, const float* __restrict__ a_dst,
        float* __restrict__ al_s, float* __restrict__ al_d){
    int n = blockIdx.x * 4 + (threadIdx.x >> 6);
    int lane = threadIdx.x & 63;
    if (n >= N_NODES) return;
    short8 v = *(const short8*)(h1b + (size_t)n * HH + lane * 8);
    int head = lane >> 3;
    int j0 = (lane & 7) * 8;
    float ps = 0.f, pd = 0.f;
#pragma unroll
    for (int j = 0; j < 8; j++){
        float hv = bf2f((unsigned short)v[j]);
        ps += hv * a_src[head * HID + j0 + j];
        pd += hv * a_dst[head * HID + j0 + j];
    }
#pragma unroll
    for (int off = 1; off < 8; off <<= 1){
        ps += __shfl_xor(ps, off);
        pd += __shfl_xor(pd, off);
    }
    if ((lane & 7) == 0){
        al_s[n * HEADS + head] = ps;
        al_d[n * HEADS + head] = pd;
    }
}

// ---------------- layer-1 aggregation + softmax + elu -> x2b bf16 [N][512] ----------------
// one block per dst node; 8 groups of 32 lanes, one head per group (2 cols/lane).
__global__ __launch_bounds__(256) void l1_agg(const unsigned short* __restrict__ h1b,
        const float* __restrict__ al_s, const float* __restrict__ al_d,
        const int* __restrict__ offsets, const int* __restrict__ esrc,
        const float* __restrict__ b1, unsigned short* __restrict__ x2b){
    int d = blockIdx.x;
    int g  = threadIdx.x >> 5;
    int sl = threadIdx.x & 31;
    int off = offsets[d], deg = offsets[d + 1] - off;
    float ald = al_d[d * HEADS + g];
    float aself = lrelu(al_s[d * HEADS + g] + ald);
    float m = aself;
    for (int i = 0; i < deg; i++){
        int s = esrc[off + i];
        m = fmaxf(m, lrelu(al_s[s * HEADS + g] + ald));
    }
    float w = __expf(aself - m);
    float denom = w;
    float acc0, acc1;
    {
        unsigned int pv = *(const unsigned int*)(h1b + (size_t)d * HH + g * HID + sl * 2);
        acc0 = w * bf2f((unsigned short)(pv & 0xffff));
        acc1 = w * bf2f((unsigned short)(pv >> 16));
    }
    for (int i = 0; i < deg; i++){
        int s = esrc[off + i];
        float a = lrelu(al_s[s * HEADS + g] + ald);
        w = __expf(a - m);
        denom += w;
        unsigned int pv = *(const unsigned int*)(h1b + (size_t)s * HH + g * HID + sl * 2);
        acc0 += w * bf2f((unsigned short)(pv & 0xffff));
        acc1 += w * bf2f((unsigned short)(pv >> 16));
    }
    float inv = 1.f / denom;
    float v0 = acc0 * inv + b1[g * HID + sl * 2];
    float v1 = acc1 * inv + b1[g * HID + sl * 2 + 1];
    v0 = v0 > 0.f ? v0 : __expf(v0) - 1.f;   // elu
    v1 = v1 > 0.f ? v1 : __expf(v1) - 1.f;
    unsigned int o = ((unsigned int)f2bf(v1) << 16) | f2bf(v0);
    *(unsigned int*)(x2b + (size_t)d * HH + g * HID + sl * 2) = o;
}

// ---------------- layer-2 GEMM (K=512 -> 16) + attention dots ----------------
__global__ __launch_bounds__(256) void gemm2(const unsigned short* __restrict__ x2b,
        const float* __restrict__ W2, const float* __restrict__ a_s2, const float* __restrict__ a_d2,
        float* __restrict__ h2, float* __restrict__ al2s, float* __restrict__ al2d){
    __shared__ float w2s[HH * NCLS];
    for (int i = threadIdx.x; i < HH * NCLS; i += 256) w2s[i] = W2[i];
    __syncthreads();
    int n = blockIdx.x * 4 + (threadIdx.x >> 6);
    int lane = threadIdx.x & 63;
    if (n >= N_NODES) return;
    short8 v = *(const short8*)(x2b + (size_t)n * HH + lane * 8);
    float p[NCLS];
#pragma unroll
    for (int j = 0; j < NCLS; j++) p[j] = 0.f;
#pragma unroll
    for (int jj = 0; jj < 8; jj++){
        float xv = bf2f((unsigned short)v[jj]);
        int c = lane * 8 + jj;
#pragma unroll
        for (int j = 0; j < NCLS; j++) p[j] += xv * w2s[c * NCLS + j];
    }
#pragma unroll
    for (int off = 1; off < 64; off <<= 1){
#pragma unroll
        for (int j = 0; j < NCLS; j++) p[j] += __shfl_xor(p[j], off);
    }
    if (lane < NCLS) h2[n * NCLS + lane] = p[lane];
    if (lane == 0){
        float s = 0.f, dd = 0.f;
#pragma unroll
        for (int j = 0; j < NCLS; j++){ s += p[j] * a_s2[j]; dd += p[j] * a_d2[j]; }
        al2s[n] = s; al2d[n] = dd;
    }
}

// ---------------- layer-2 aggregation -> out [N][16] fp32 ----------------
// one wave per dst; 4 subgroups of 16 lanes process 4 edges in parallel.
__global__ __launch_bounds__(256) void l2_agg(const float* __restrict__ h2,
        const float* __restrict__ al2s, const float* __restrict__ al2d,
        const int* __restrict__ offsets, const int* __restrict__ esrc,
        const float* __restrict__ b2, float* __restrict__ out){
    int d = blockIdx.x * 4 + (threadIdx.x >> 6);
    int lane = threadIdx.x & 63;
    if (d >= N_NODES) return;
    int off = offsets[d], deg = offsets[d + 1] - off;
    float ald = al2d[d];
    float a0 = lrelu(al2s[d] + ald);
    float m = a0;
    for (int base = 0; base < deg; base += 64){
        int i = base + lane;
        float a = -1e30f;
        if (i < deg) a = lrelu(al2s[esrc[off + i]] + ald);
#pragma unroll
        for (int o2 = 1; o2 < 64; o2 <<= 1) a = fmaxf(a, __shfl_xor(a, o2));
        m = fmaxf(m, a);
    }
    float dsum = __expf(a0 - m);
    for (int base = 0; base < deg; base += 64){
        int i = base + lane;
        float w = 0.f;
        if (i < deg) w = __expf(lrelu(al2s[esrc[off + i]] + ald) - m);
#pragma unroll
        for (int o2 = 1; o2 < 64; o2 <<= 1) w += __shfl_xor(w, o2);
        dsum += w;
    }
    int sg = lane >> 4, col = lane & 15;
    float acc = (sg == 0) ? __expf(a0 - m) * h2[d * NCLS + col] : 0.f;
    for (int base = 0; base < deg; base += 4){
        int i = base + sg;
        if (i < deg){
            int s = esrc[off + i];
            float w = __expf(lrelu(al2s[s] + ald) - m);
            acc += w * h2[s * NCLS + col];
        }
    }
    acc += __shfl_xor(acc, 16);
    acc += __shfl_xor(acc, 32);
    if (lane < NCLS) out[d * NCLS + lane] = acc / dsum + b2[lane];
}

extern "C" void kernel_launch(void* const* d_in, const int* in_sizes, int n_in,
                              void* d_out, int out_size, void* d_ws, size_t ws_size,
                              hipStream_t stream){
    const float* x   = (const float*)d_in[0];
    const int*   ei  = (const int*)d_in[1];
    const int*   src = ei;
    const int*   dst = ei + NEDGE;
    const float* W1  = (const float*)d_in[2];
    const float* as1 = (const float*)d_in[3];
    const float* ad1 = (const float*)d_in[4];
    const float* b1  = (const float*)d_in[5];
    const float* W2  = (const float*)d_in[6];
    const float* as2 = (const float*)d_in[7];
    const float* ad2 = (const float*)d_in[8];
    const float* b2  = (const float*)d_in[9];
    float* out = (float*)d_out;

    char* p = (char*)d_ws;
    auto carve = [&](size_t bytes) -> char* {
        char* r = p; p += (bytes + 255) & ~(size_t)255; return r;
    };
    unsigned short* xb   = (unsigned short*)carve((size_t)N_NODES * F_INK * 2);
    unsigned short* w1t  = (unsigned short*)carve((size_t)HH * F_INK * 2);
    unsigned short* h1b  = (unsigned short*)carve((size_t)N_NODES * HH * 2);
    float* al1s  = (float*)carve((size_t)N_NODES * HEADS * 4);
    float* al1d  = (float*)carve((size_t)N_NODES * HEADS * 4);
    int* counts  = (int*)carve((size_t)N_NODES * 4);
    int* cursor  = (int*)carve((size_t)N_NODES * 4);
    int* offsets = (int*)carve((size_t)(N_NODES + 1) * 4);
    int* esrc    = (int*)carve((size_t)NEDGE * 4);
    unsigned short* x2b = (unsigned short*)carve((size_t)N_NODES * HH * 2);
    float* h2    = (float*)carve((size_t)N_NODES * NCLS * 4);
    float* al2s  = (float*)carve((size_t)N_NODES * 4);
    float* al2d  = (float*)carve((size_t)N_NODES * 4);
    if ((size_t)(p - (char*)d_ws) > ws_size) return;  // workspace too small

    hipMemsetAsync(counts, 0, N_NODES * 4, stream);
    hipMemsetAsync(cursor, 0, N_NODES * 4, stream);

    cvt_f32_bf16<<<2048, 256, 0, stream>>>(x, xb, N_NODES * F_INK);
    cvt_w1t<<<(F_INK * HH + 255) / 256, 256, 0, stream>>>(W1, w1t);
    count_edges<<<(NEDGE + 255) / 256, 256, 0, stream>>>(dst, counts);
    scan_offsets<<<1, 1024, 0, stream>>>(counts, offsets);
    scatter_edges<<<(NEDGE + 255) / 256, 256, 0, stream>>>(src, dst, offsets, cursor, esrc);
    gemm1<<<(N_NODES / 16 + 3) / 4, 256, 0, stream>>>(xb, w1t, h1b);
    attn1_dots<<<(N_NODES + 3) / 4, 256, 0, stream>>>(h1b, as1, ad1, al1s, al1d);
    l1_agg<<<N_NODES, 256, 0, stream>>>(h1b, al1s, al1d, offsets, esrc, b1, x2b);
    gemm2<<<(N_NODES + 3) / 4, 256, 0, stream>>>(x2b, W2, as2, ad2, h2, al2s, al2d);
    l2_agg<<<(N_NODES + 3) / 4, 256, 0, stream>>>(h2, al2s, al2d, offsets, esrc, b2, out);
}

// Round 2
// 492.740 us; speedup vs baseline: 1.4199x; 1.4199x over previous
//
#include <hip/hip_runtime.h>
#include <hip/hip_bf16.h>
#include <math.h>

#define N_NODES 50000
#define F_INK   256
#define HEADS   8
#define HID     64
#define HH      512     // HEADS*HID
#define NCLS    16
#define NEDGE   400000
#define NEG_SLOPE 0.2f

typedef __attribute__((ext_vector_type(8))) short short8;
typedef __attribute__((ext_vector_type(4))) float float4v;

__device__ __forceinline__ float bf2f(unsigned short u){
    unsigned int x = ((unsigned int)u) << 16;
    float f; __builtin_memcpy(&f, &x, 4); return f;
}
__device__ __forceinline__ unsigned short f2bf(float f){
    unsigned int x; __builtin_memcpy(&x, &f, 4);
    unsigned int r = x + 0x7FFFu + ((x >> 16) & 1u);   // RNE
    return (unsigned short)(r >> 16);
}
__device__ __forceinline__ float lrelu(float a){ return a > 0.f ? a : NEG_SLOPE * a; }

// ---------------- conversions ----------------
__global__ void cvt_f32_bf16(const float* __restrict__ in, unsigned short* __restrict__ out, int n){
    int i = blockIdx.x * blockDim.x + threadIdx.x;
    int stride = gridDim.x * blockDim.x;
    for (; i < n; i += stride) out[i] = f2bf(in[i]);
}

// W1 [256][512] fp32 -> W1T [512][256] bf16
__global__ void cvt_w1t(const float* __restrict__ W1, unsigned short* __restrict__ W1T){
    int i = blockIdx.x * blockDim.x + threadIdx.x;
    if (i >= F_INK * HH) return;
    int k = i / HH, c = i % HH;
    W1T[c * F_INK + k] = f2bf(W1[i]);
}

// W2 [512][16] fp32 -> W2T [16][512] bf16
__global__ void cvt_w2t(const float* __restrict__ W2, unsigned short* __restrict__ W2T){
    int i = blockIdx.x * blockDim.x + threadIdx.x;
    if (i >= HH * NCLS) return;
    int k = i / NCLS, c = i % NCLS;
    W2T[c * HH + k] = f2bf(W2[i]);
}

// ---------------- CSR build ----------------
__global__ void count_edges(const int* __restrict__ dst, int* __restrict__ counts){
    int e = blockIdx.x * blockDim.x + threadIdx.x;
    if (e < NEDGE) atomicAdd(&counts[dst[e]], 1);
}

__global__ void scan_offsets(const int* __restrict__ counts, int* __restrict__ offsets){
    __shared__ int tsum[1024];
    int t = threadIdx.x;
    const int per = (N_NODES + 1023) / 1024;
    int begin = t * per;
    int end = begin + per; if (end > N_NODES) end = N_NODES;
    int s = 0;
    if (begin < N_NODES) for (int i = begin; i < end; i++) s += counts[i];
    tsum[t] = s; __syncthreads();
    int val = s;
    for (int off = 1; off < 1024; off <<= 1){
        int v2 = (t >= off) ? tsum[t - off] : 0;
        __syncthreads();
        val += v2; tsum[t] = val;
        __syncthreads();
    }
    int run = val - s;
    if (begin < N_NODES) for (int i = begin; i < end; i++){ offsets[i] = run; run += counts[i]; }
    if (t == 0) offsets[N_NODES] = tsum[1023];
}

__global__ void scatter_edges(const int* __restrict__ src, const int* __restrict__ dst,
                              const int* __restrict__ offsets, int* __restrict__ cursor,
                              int* __restrict__ esrc){
    int e = blockIdx.x * blockDim.x + threadIdx.x;
    if (e < NEDGE){
        int d = dst[e];
        int pos = offsets[d] + atomicAdd(&cursor[d], 1);
        esrc[pos] = src[e];
    }
}

// ---------------- GEMM1: h1 = bf16(x) @ bf16(W1), output bf16 [N][512] ----------------
// one wave computes a 16-row tile over all 512 cols; K=256 held in registers.
__global__ __launch_bounds__(256) void gemm1(const unsigned short* __restrict__ xb,
                                             const unsigned short* __restrict__ w1t,
                                             unsigned short* __restrict__ h1b){
    int wave = (blockIdx.x * blockDim.x + threadIdx.x) >> 6;
    int lane = threadIdx.x & 63;
    if (wave >= N_NODES / 16) return;
    int rowbase = wave * 16;
    int lr = lane & 15, lk = lane >> 4;
    short8 a[8];
#pragma unroll
    for (int ks = 0; ks < 8; ks++)
        a[ks] = *(const short8*)(xb + (size_t)(rowbase + lr) * F_INK + ks * 32 + lk * 8);
    for (int ct = 0; ct < 32; ct++){
        float4v acc = {0.f, 0.f, 0.f, 0.f};
#pragma unroll
        for (int ks = 0; ks < 8; ks++){
            short8 b = *(const short8*)(w1t + (size_t)(ct * 16 + lr) * F_INK + ks * 32 + lk * 8);
            acc = __builtin_amdgcn_mfma_f32_16x16x32_bf16(a[ks], b, acc, 0, 0, 0);
        }
#pragma unroll
        for (int r = 0; r < 4; r++)
            h1b[(size_t)(rowbase + lk * 4 + r) * HH + ct * 16 + lr] = f2bf(acc[r]);
    }
}

// ---------------- attention dots: al_src/al_dst [N][8] ----------------
__global__ __launch_bounds__(256) void attn1_dots(const unsigned short* __restrict__ h1b,
        const float* __restrict__ a_src, const float* __restrict__ a_dst,
        float* __restrict__ al_s, float* __restrict__ al_d){
    int n = blockIdx.x * 4 + (threadIdx.x >> 6);
    int lane = threadIdx.x & 63;
    if (n >= N_NODES) return;
    short8 v = *(const short8*)(h1b + (size_t)n * HH + lane * 8);
    int head = lane >> 3;
    int j0 = (lane & 7) * 8;
    float ps = 0.f, pd = 0.f;
#pragma unroll
    for (int j = 0; j < 8; j++){
        float hv = bf2f((unsigned short)v[j]);
        ps += hv * a_src[head * HID + j0 + j];
        pd += hv * a_dst[head * HID + j0 + j];
    }
#pragma unroll
    for (int off = 1; off < 8; off <<= 1){
        ps += __shfl_xor(ps, off);
        pd += __shfl_xor(pd, off);
    }
    if ((lane & 7) == 0){
        al_s[n * HEADS + head] = ps;
        al_d[n * HEADS + head] = pd;
    }
}

// ---------------- layer-1 aggregation + softmax + elu -> x2b bf16 [N][512] ----------------
// one block per dst node; 8 groups of 32 lanes, one head per group (2 cols/lane).
__global__ __launch_bounds__(256) void l1_agg(const unsigned short* __restrict__ h1b,
        const float* __restrict__ al_s, const float* __restrict__ al_d,
        const int* __restrict__ offsets, const int* __restrict__ esrc,
        const float* __restrict__ b1, unsigned short* __restrict__ x2b){
    int d = blockIdx.x;
    int g  = threadIdx.x >> 5;
    int sl = threadIdx.x & 31;
    int off = offsets[d], deg = offsets[d + 1] - off;
    float ald = al_d[d * HEADS + g];
    float aself = lrelu(al_s[d * HEADS + g] + ald);
    float m = aself;
    for (int i = 0; i < deg; i++){
        int s = esrc[off + i];
        m = fmaxf(m, lrelu(al_s[s * HEADS + g] + ald));
    }
    float w = __expf(aself - m);
    float denom = w;
    float acc0, acc1;
    {
        unsigned int pv = *(const unsigned int*)(h1b + (size_t)d * HH + g * HID + sl * 2);
        acc0 = w * bf2f((unsigned short)(pv & 0xffff));
        acc1 = w * bf2f((unsigned short)(pv >> 16));
    }
    for (int i = 0; i < deg; i++){
        int s = esrc[off + i];
        float a = lrelu(al_s[s * HEADS + g] + ald);
        w = __expf(a - m);
        denom += w;
        unsigned int pv = *(const unsigned int*)(h1b + (size_t)s * HH + g * HID + sl * 2);
        acc0 += w * bf2f((unsigned short)(pv & 0xffff));
        acc1 += w * bf2f((unsigned short)(pv >> 16));
    }
    float inv = 1.f / denom;
    float v0 = acc0 * inv + b1[g * HID + sl * 2];
    float v1 = acc1 * inv + b1[g * HID + sl * 2 + 1];
    v0 = v0 > 0.f ? v0 : __expf(v0) - 1.f;   // elu
    v1 = v1 > 0.f ? v1 : __expf(v1) - 1.f;
    unsigned int o = ((unsigned int)f2bf(v1) << 16) | f2bf(v0);
    *(unsigned int*)(x2b + (size_t)d * HH + g * HID + sl * 2) = o;
}

// ---------------- layer-2 GEMM via MFMA: h2 = x2b @ W2 (+ fused attention dots) --------
// one wave per 16-row tile; K=512 -> 16 MFMA; W2T bf16 [16][512] is L2-resident (16 KB).
__global__ __launch_bounds__(256) void gemm2(const unsigned short* __restrict__ x2b,
        const unsigned short* __restrict__ w2t,
        const float* __restrict__ a_s2, const float* __restrict__ a_d2,
        float* __restrict__ h2, float* __restrict__ al2s, float* __restrict__ al2d){
    int wave = (blockIdx.x * blockDim.x + threadIdx.x) >> 6;
    int lane = threadIdx.x & 63;
    if (wave >= N_NODES / 16) return;           // 50000/16 = 3125 exactly
    int rowbase = wave * 16;
    int lr = lane & 15, lk = lane >> 4;
    float4v acc = {0.f, 0.f, 0.f, 0.f};
#pragma unroll
    for (int ks = 0; ks < 16; ks++){
        short8 a = *(const short8*)(x2b + (size_t)(rowbase + lr) * HH + ks * 32 + lk * 8);
        short8 b = *(const short8*)(w2t + (size_t)lr * HH + ks * 32 + lk * 8);
        acc = __builtin_amdgcn_mfma_f32_16x16x32_bf16(a, b, acc, 0, 0, 0);
    }
    // C/D layout: col = lane&15 (=lr), row = lk*4 + r
#pragma unroll
    for (int r = 0; r < 4; r++)
        h2[(size_t)(rowbase + lk * 4 + r) * NCLS + lr] = acc[r];
    float s_a = a_s2[lr], d_a = a_d2[lr];
#pragma unroll
    for (int r = 0; r < 4; r++){
        float ps = acc[r] * s_a, pd = acc[r] * d_a;
#pragma unroll
        for (int off = 1; off < 16; off <<= 1){
            ps += __shfl_xor(ps, off);
            pd += __shfl_xor(pd, off);
        }
        if (lr == 0){
            al2s[rowbase + lk * 4 + r] = ps;
            al2d[rowbase + lk * 4 + r] = pd;
        }
    }
}

// ---------------- layer-2 aggregation -> out [N][16] fp32 ----------------
// one wave per dst; 4 subgroups of 16 lanes process 4 edges in parallel.
__global__ __launch_bounds__(256) void l2_agg(const float* __restrict__ h2,
        const float* __restrict__ al2s, const float* __restrict__ al2d,
        const int* __restrict__ offsets, const int* __restrict__ esrc,
        const float* __restrict__ b2, float* __restrict__ out){
    int d = blockIdx.x * 4 + (threadIdx.x >> 6);
    int lane = threadIdx.x & 63;
    if (d >= N_NODES) return;
    int off = offsets[d], deg = offsets[d + 1] - off;
    float ald = al2d[d];
    float a0 = lrelu(al2s[d] + ald);
    float m = a0;
    for (int base = 0; base < deg; base += 64){
        int i = base + lane;
        float a = -1e30f;
        if (i < deg) a = lrelu(al2s[esrc[off + i]] + ald);
#pragma unroll
        for (int o2 = 1; o2 < 64; o2 <<= 1) a = fmaxf(a, __shfl_xor(a, o2));
        m = fmaxf(m, a);
    }
    float dsum = __expf(a0 - m);
    for (int base = 0; base < deg; base += 64){
        int i = base + lane;
        float w = 0.f;
        if (i < deg) w = __expf(lrelu(al2s[esrc[off + i]] + ald) - m);
#pragma unroll
        for (int o2 = 1; o2 < 64; o2 <<= 1) w += __shfl_xor(w, o2);
        dsum += w;
    }
    int sg = lane >> 4, col = lane & 15;
    float acc = (sg == 0) ? __expf(a0 - m) * h2[d * NCLS + col] : 0.f;
    for (int base = 0; base < deg; base += 4){
        int i = base + sg;
        if (i < deg){
            int s = esrc[off + i];
            float w = __expf(lrelu(al2s[s] + ald) - m);
            acc += w * h2[s * NCLS + col];
        }
    }
    acc += __shfl_xor(acc, 16);
    acc += __shfl_xor(acc, 32);
    if (lane < NCLS) out[d * NCLS + lane] = acc / dsum + b2[lane];
}

extern "C" void kernel_launch(void* const* d_in, const int* in_sizes, int n_in,
                              void* d_out, int out_size, void* d_ws, size_t ws_size,
                              hipStream_t stream){
    const float* x   = (const float*)d_in[0];
    const int*   ei  = (const int*)d_in[1];
    const int*   src = ei;
    const int*   dst = ei + NEDGE;
    const float* W1  = (const float*)d_in[2];
    const float* as1 = (const float*)d_in[3];
    const float* ad1 = (const float*)d_in[4];
    const float* b1  = (const float*)d_in[5];
    const float* W2  = (const float*)d_in[6];
    const float* as2 = (const float*)d_in[7];
    const float* ad2 = (const float*)d_in[8];
    const float* b2  = (const float*)d_in[9];
    float* out = (float*)d_out;

    char* p = (char*)d_ws;
    auto carve = [&](size_t bytes) -> char* {
        char* r = p; p += (bytes + 255) & ~(size_t)255; return r;
    };
    unsigned short* xb   = (unsigned short*)carve((size_t)N_NODES * F_INK * 2);
    unsigned short* w1t  = (unsigned short*)carve((size_t)HH * F_INK * 2);
    unsigned short* w2t  = (unsigned short*)carve((size_t)HH * NCLS * 2);
    unsigned short* h1b  = (unsigned short*)carve((size_t)N_NODES * HH * 2);
    float* al1s  = (float*)carve((size_t)N_NODES * HEADS * 4);
    float* al1d  = (float*)carve((size_t)N_NODES * HEADS * 4);
    int* counts  = (int*)carve((size_t)N_NODES * 4);
    int* cursor  = (int*)carve((size_t)N_NODES * 4);
    int* offsets = (int*)carve((size_t)(N_NODES + 1) * 4);
    int* esrc    = (int*)carve((size_t)NEDGE * 4);
    unsigned short* x2b = (unsigned short*)carve((size_t)N_NODES * HH * 2);
    float* h2    = (float*)carve((size_t)N_NODES * NCLS * 4);
    float* al2s  = (float*)carve((size_t)N_NODES * 4);
    float* al2d  = (float*)carve((size_t)N_NODES * 4);
    if ((size_t)(p - (char*)d_ws) > ws_size) return;  // workspace too small

    hipMemsetAsync(counts, 0, N_NODES * 4, stream);
    hipMemsetAsync(cursor, 0, N_NODES * 4, stream);

    cvt_f32_bf16<<<2048, 256, 0, stream>>>(x, xb, N_NODES * F_INK);
    cvt_w1t<<<(F_INK * HH + 255) / 256, 256, 0, stream>>>(W1, w1t);
    cvt_w2t<<<(HH * NCLS + 255) / 256, 256, 0, stream>>>(W2, w2t);
    count_edges<<<(NEDGE + 255) / 256, 256, 0, stream>>>(dst, counts);
    scan_offsets<<<1, 1024, 0, stream>>>(counts, offsets);
    scatter_edges<<<(NEDGE + 255) / 256, 256, 0, stream>>>(src, dst, offsets, cursor, esrc);
    gemm1<<<(N_NODES / 16 + 3) / 4, 256, 0, stream>>>(xb, w1t, h1b);
    attn1_dots<<<(N_NODES + 3) / 4, 256, 0, stream>>>(h1b, as1, ad1, al1s, al1d);
    l1_agg<<<N_NODES, 256, 0, stream>>>(h1b, al1s, al1d, offsets, esrc, b1, x2b);
    gemm2<<<(N_NODES / 16 + 3) / 4, 256, 0, stream>>>(x2b, w2t, as2, ad2, h2, al2s, al2d);
    l2_agg<<<(N_NODES + 3) / 4, 256, 0, stream>>>(h2, al2s, al2d, offsets, esrc, b2, out);
}

// Round 3
// 452.680 us; speedup vs baseline: 1.5456x; 1.0885x over previous
//
#include <hip/hip_runtime.h>
#include <hip/hip_bf16.h>
#include <math.h>

#define N_NODES 50000
#define F_INK   256
#define HEADS   8
#define HID     64
#define HH      512     // HEADS*HID
#define NCLS    16
#define NEDGE   400000
#define NEG_SLOPE 0.2f

typedef __attribute__((ext_vector_type(8))) short short8;
typedef __attribute__((ext_vector_type(4))) float float4v;

__device__ __forceinline__ float bf2f(unsigned short u){
    unsigned int x = ((unsigned int)u) << 16;
    float f; __builtin_memcpy(&f, &x, 4); return f;
}
__device__ __forceinline__ unsigned short f2bf(float f){
    unsigned int x; __builtin_memcpy(&x, &f, 4);
    unsigned int r = x + 0x7FFFu + ((x >> 16) & 1u);   // RNE
    return (unsigned short)(r >> 16);
}
__device__ __forceinline__ float lrelu(float a){ return a > 0.f ? a : NEG_SLOPE * a; }

// ---------------- conversions ----------------
__global__ void cvt_f32_bf16(const float* __restrict__ in, unsigned short* __restrict__ out, int n){
    int i = blockIdx.x * blockDim.x + threadIdx.x;
    int stride = gridDim.x * blockDim.x;
    for (; i < n; i += stride) out[i] = f2bf(in[i]);
}

// W1 [256][512] fp32 -> W1T [512][256] bf16
__global__ void cvt_w1t(const float* __restrict__ W1, unsigned short* __restrict__ W1T){
    int i = blockIdx.x * blockDim.x + threadIdx.x;
    if (i >= F_INK * HH) return;
    int k = i / HH, c = i % HH;
    W1T[c * F_INK + k] = f2bf(W1[i]);
}

// W2 [512][16] fp32 -> W2T [16][512] bf16
__global__ void cvt_w2t(const float* __restrict__ W2, unsigned short* __restrict__ W2T){
    int i = blockIdx.x * blockDim.x + threadIdx.x;
    if (i >= HH * NCLS) return;
    int k = i / NCLS, c = i % NCLS;
    W2T[c * HH + k] = f2bf(W2[i]);
}

// ---------------- CSR build ----------------
__global__ void count_edges(const int* __restrict__ dst, int* __restrict__ counts){
    int e = blockIdx.x * blockDim.x + threadIdx.x;
    if (e < NEDGE) atomicAdd(&counts[dst[e]], 1);
}

__global__ void scan_offsets(const int* __restrict__ counts, int* __restrict__ offsets){
    __shared__ int tsum[1024];
    int t = threadIdx.x;
    const int per = (N_NODES + 1023) / 1024;
    int begin = t * per;
    int end = begin + per; if (end > N_NODES) end = N_NODES;
    int s = 0;
    if (begin < N_NODES) for (int i = begin; i < end; i++) s += counts[i];
    tsum[t] = s; __syncthreads();
    int val = s;
    for (int off = 1; off < 1024; off <<= 1){
        int v2 = (t >= off) ? tsum[t - off] : 0;
        __syncthreads();
        val += v2; tsum[t] = val;
        __syncthreads();
    }
    int run = val - s;
    if (begin < N_NODES) for (int i = begin; i < end; i++){ offsets[i] = run; run += counts[i]; }
    if (t == 0) offsets[N_NODES] = tsum[1023];
}

__global__ void scatter_edges(const int* __restrict__ src, const int* __restrict__ dst,
                              const int* __restrict__ offsets, int* __restrict__ cursor,
                              int* __restrict__ esrc){
    int e = blockIdx.x * blockDim.x + threadIdx.x;
    if (e < NEDGE){
        int d = dst[e];
        int pos = offsets[d] + atomicAdd(&cursor[d], 1);
        esrc[pos] = src[e];
    }
}

// ---------------- GEMM1: h1 = bf16(x) @ bf16(W1), output bf16 [N][512] ----------------
__global__ __launch_bounds__(256) void gemm1(const unsigned short* __restrict__ xb,
                                             const unsigned short* __restrict__ w1t,
                                             unsigned short* __restrict__ h1b){
    int wave = (blockIdx.x * blockDim.x + threadIdx.x) >> 6;
    int lane = threadIdx.x & 63;
    if (wave >= N_NODES / 16) return;
    int rowbase = wave * 16;
    int lr = lane & 15, lk = lane >> 4;
    short8 a[8];
#pragma unroll
    for (int ks = 0; ks < 8; ks++)
        a[ks] = *(const short8*)(xb + (size_t)(rowbase + lr) * F_INK + ks * 32 + lk * 8);
    for (int ct = 0; ct < 32; ct++){
        float4v acc = {0.f, 0.f, 0.f, 0.f};
#pragma unroll
        for (int ks = 0; ks < 8; ks++){
            short8 b = *(const short8*)(w1t + (size_t)(ct * 16 + lr) * F_INK + ks * 32 + lk * 8);
            acc = __builtin_amdgcn_mfma_f32_16x16x32_bf16(a[ks], b, acc, 0, 0, 0);
        }
#pragma unroll
        for (int r = 0; r < 4; r++)
            h1b[(size_t)(rowbase + lk * 4 + r) * HH + ct * 16 + lr] = f2bf(acc[r]);
    }
}

// ---------------- attention dots: al_src/al_dst [N][8] ----------------
__global__ __launch_bounds__(256) void attn1_dots(const unsigned short* __restrict__ h1b,
        const float* __restrict__ a_src, const float* __restrict__ a_dst,
        float* __restrict__ al_s, float* __restrict__ al_d){
    int n = blockIdx.x * 4 + (threadIdx.x >> 6);
    int lane = threadIdx.x & 63;
    if (n >= N_NODES) return;
    short8 v = *(const short8*)(h1b + (size_t)n * HH + lane * 8);
    int head = lane >> 3;
    int j0 = (lane & 7) * 8;
    float ps = 0.f, pd = 0.f;
#pragma unroll
    for (int j = 0; j < 8; j++){
        float hv = bf2f((unsigned short)v[j]);
        ps += hv * a_src[head * HID + j0 + j];
        pd += hv * a_dst[head * HID + j0 + j];
    }
#pragma unroll
    for (int off = 1; off < 8; off <<= 1){
        ps += __shfl_xor(ps, off);
        pd += __shfl_xor(pd, off);
    }
    if ((lane & 7) == 0){
        al_s[n * HEADS + head] = ps;
        al_d[n * HEADS + head] = pd;
    }
}

// ---------------- layer-1 softmax weights: ew[p][8], wself[d][8] ----------------
// one wave per dst; lane = (i<<3)|h : 8 edges in flight x 8 heads.
__global__ __launch_bounds__(256) void softmax1(
        const float* __restrict__ al_s, const float* __restrict__ al_d,
        const int* __restrict__ offsets, const int* __restrict__ esrc,
        float* __restrict__ ew, float* __restrict__ wself){
    int d = blockIdx.x * 4 + (threadIdx.x >> 6);
    int lane = threadIdx.x & 63;
    if (d >= N_NODES) return;
    int h = lane & 7, i = lane >> 3;
    int off = offsets[d], deg = offsets[d + 1] - off;
    float ald = al_d[d * HEADS + h];
    float aself = lrelu(al_s[d * HEADS + h] + ald);
    float m = aself;
    for (int base = 0; base < deg; base += 8){
        int e = base + i;
        float a = -1e30f;
        if (e < deg) a = lrelu(al_s[esrc[off + e] * HEADS + h] + ald);
        a = fmaxf(a, __shfl_xor(a, 8));
        a = fmaxf(a, __shfl_xor(a, 16));
        a = fmaxf(a, __shfl_xor(a, 32));
        m = fmaxf(m, a);
    }
    float denom = __expf(aself - m);
    for (int base = 0; base < deg; base += 8){
        int e = base + i;
        float w = 0.f;
        if (e < deg){
            w = __expf(lrelu(al_s[esrc[off + e] * HEADS + h] + ald) - m);
            ew[(size_t)(off + e) * HEADS + h] = w;
        }
        float ws = w;
        ws += __shfl_xor(ws, 8);
        ws += __shfl_xor(ws, 16);
        ws += __shfl_xor(ws, 32);
        denom += ws;
    }
    float inv = 1.f / denom;
    if (i == 0) wself[d * HEADS + h] = __expf(aself - m) * inv;
    for (int base = 0; base < deg; base += 8){
        int e = base + i;
        if (e < deg) ew[(size_t)(off + e) * HEADS + h] *= inv;
    }
}

// ---------------- layer-1 aggregation (precomputed weights) + elu -> x2b ----------------
// one block per dst; 8 head-groups of 32 lanes; edges staged in LDS per 32-chunk.
__global__ __launch_bounds__(256) void agg1(const unsigned short* __restrict__ h1b,
        const float* __restrict__ ew, const float* __restrict__ wself,
        const int* __restrict__ offsets, const int* __restrict__ esrc,
        const float* __restrict__ b1, unsigned short* __restrict__ x2b){
    __shared__ int   s_src[32];
    __shared__ float s_w[32][HEADS];
    int d = blockIdx.x;
    int g  = threadIdx.x >> 5;
    int sl = threadIdx.x & 31;
    int off = offsets[d], deg = offsets[d + 1] - off;
    float w0 = wself[d * HEADS + g];
    unsigned int pv = *(const unsigned int*)(h1b + (size_t)d * HH + g * HID + sl * 2);
    float acc0 = w0 * bf2f((unsigned short)(pv & 0xffff));
    float acc1 = w0 * bf2f((unsigned short)(pv >> 16));
    for (int base = 0; base < deg; base += 32){
        int m2 = deg - base; if (m2 > 32) m2 = 32;
        __syncthreads();
        if (threadIdx.x < m2) s_src[threadIdx.x] = esrc[off + base + threadIdx.x];
        {
            int k = threadIdx.x >> 3, j = threadIdx.x & 7;
            if (k < m2) s_w[k][j] = ew[(size_t)(off + base + k) * HEADS + j];
        }
        __syncthreads();
        for (int i2 = 0; i2 < m2; i2++){
            int s = s_src[i2];
            float w = s_w[i2][g];
            unsigned int p2 = *(const unsigned int*)(h1b + (size_t)s * HH + g * HID + sl * 2);
            acc0 += w * bf2f((unsigned short)(p2 & 0xffff));
            acc1 += w * bf2f((unsigned short)(p2 >> 16));
        }
    }
    float v0 = acc0 + b1[g * HID + sl * 2];
    float v1 = acc1 + b1[g * HID + sl * 2 + 1];
    v0 = v0 > 0.f ? v0 : __expf(v0) - 1.f;   // elu
    v1 = v1 > 0.f ? v1 : __expf(v1) - 1.f;
    unsigned int o = ((unsigned int)f2bf(v1) << 16) | f2bf(v0);
    *(unsigned int*)(x2b + (size_t)d * HH + g * HID + sl * 2) = o;
}

// ---------------- layer-2 GEMM via MFMA: h2 = x2b @ W2 (+ fused attention dots) --------
__global__ __launch_bounds__(256) void gemm2(const unsigned short* __restrict__ x2b,
        const unsigned short* __restrict__ w2t,
        const float* __restrict__ a_s2, const float* __restrict__ a_d2,
        float* __restrict__ h2, float* __restrict__ al2s, float* __restrict__ al2d){
    int wave = (blockIdx.x * blockDim.x + threadIdx.x) >> 6;
    int lane = threadIdx.x & 63;
    if (wave >= N_NODES / 16) return;
    int rowbase = wave * 16;
    int lr = lane & 15, lk = lane >> 4;
    float4v acc = {0.f, 0.f, 0.f, 0.f};
#pragma unroll
    for (int ks = 0; ks < 16; ks++){
        short8 a = *(const short8*)(x2b + (size_t)(rowbase + lr) * HH + ks * 32 + lk * 8);
        short8 b = *(const short8*)(w2t + (size_t)lr * HH + ks * 32 + lk * 8);
        acc = __builtin_amdgcn_mfma_f32_16x16x32_bf16(a, b, acc, 0, 0, 0);
    }
#pragma unroll
    for (int r = 0; r < 4; r++)
        h2[(size_t)(rowbase + lk * 4 + r) * NCLS + lr] = acc[r];
    float s_a = a_s2[lr], d_a = a_d2[lr];
#pragma unroll
    for (int r = 0; r < 4; r++){
        float ps = acc[r] * s_a, pd = acc[r] * d_a;
#pragma unroll
        for (int off = 1; off < 16; off <<= 1){
            ps += __shfl_xor(ps, off);
            pd += __shfl_xor(pd, off);
        }
        if (lr == 0){
            al2s[rowbase + lk * 4 + r] = ps;
            al2d[rowbase + lk * 4 + r] = pd;
        }
    }
}

// ---------------- layer-2 softmax weights ----------------
__global__ __launch_bounds__(256) void softmax2(
        const float* __restrict__ al2s, const float* __restrict__ al2d,
        const int* __restrict__ offsets, const int* __restrict__ esrc,
        float* __restrict__ ew2, float* __restrict__ wself2){
    int d = blockIdx.x * 4 + (threadIdx.x >> 6);
    int lane = threadIdx.x & 63;
    if (d >= N_NODES) return;
    int off = offsets[d], deg = offsets[d + 1] - off;
    float ald = al2d[d];
    float aself = lrelu(al2s[d] + ald);
    float m = aself;
    for (int base = 0; base < deg; base += 64){
        int e = base + lane;
        float a = (e < deg) ? lrelu(al2s[esrc[off + e]] + ald) : -1e30f;
#pragma unroll
        for (int o = 1; o < 64; o <<= 1) a = fmaxf(a, __shfl_xor(a, o));
        m = fmaxf(m, a);
    }
    float denom = __expf(aself - m);
    for (int base = 0; base < deg; base += 64){
        int e = base + lane;
        float w = 0.f;
        if (e < deg){
            w = __expf(lrelu(al2s[esrc[off + e]] + ald) - m);
            ew2[off + e] = w;
        }
#pragma unroll
        for (int o = 1; o < 64; o <<= 1) w += __shfl_xor(w, o);
        denom += w;
    }
    float inv = 1.f / denom;
    if (lane == 0) wself2[d] = __expf(aself - m) * inv;
    for (int base = 0; base < deg; base += 64){
        int e = base + lane;
        if (e < deg) ew2[off + e] *= inv;
    }
}

// ---------------- layer-2 aggregation -> out [N][16] fp32 ----------------
__global__ __launch_bounds__(256) void agg2(const float* __restrict__ h2,
        const float* __restrict__ ew2, const float* __restrict__ wself2,
        const int* __restrict__ offsets, const int* __restrict__ esrc,
        const float* __restrict__ b2, float* __restrict__ out){
    int d = blockIdx.x * 4 + (threadIdx.x >> 6);
    int lane = threadIdx.x & 63;
    if (d >= N_NODES) return;
    int off = offsets[d], deg = offsets[d + 1] - off;
    int sg = lane >> 4, col = lane & 15;
    float acc = (sg == 0) ? wself2[d] * h2[(size_t)d * NCLS + col] : 0.f;
    for (int base = 0; base < deg; base += 4){
        int i = base + sg;
        if (i < deg){
            int s = esrc[off + i];
            acc += ew2[off + i] * h2[(size_t)s * NCLS + col];
        }
    }
    acc += __shfl_xor(acc, 16);
    acc += __shfl_xor(acc, 32);
    if (lane < NCLS) out[(size_t)d * NCLS + lane] = acc + b2[lane];
}

extern "C" void kernel_launch(void* const* d_in, const int* in_sizes, int n_in,
                              void* d_out, int out_size, void* d_ws, size_t ws_size,
                              hipStream_t stream){
    const float* x   = (const float*)d_in[0];
    const int*   ei  = (const int*)d_in[1];
    const int*   src = ei;
    const int*   dst = ei + NEDGE;
    const float* W1  = (const float*)d_in[2];
    const float* as1 = (const float*)d_in[3];
    const float* ad1 = (const float*)d_in[4];
    const float* b1  = (const float*)d_in[5];
    const float* W2  = (const float*)d_in[6];
    const float* as2 = (const float*)d_in[7];
    const float* ad2 = (const float*)d_in[8];
    const float* b2  = (const float*)d_in[9];
    float* out = (float*)d_out;

    char* p = (char*)d_ws;
    auto carve = [&](size_t bytes) -> char* {
        char* r = p; p += (bytes + 255) & ~(size_t)255; return r;
    };
    unsigned short* xb   = (unsigned short*)carve((size_t)N_NODES * F_INK * 2);
    unsigned short* w1t  = (unsigned short*)carve((size_t)HH * F_INK * 2);
    unsigned short* w2t  = (unsigned short*)carve((size_t)HH * NCLS * 2);
    unsigned short* h1b  = (unsigned short*)carve((size_t)N_NODES * HH * 2);
    float* al1s  = (float*)carve((size_t)N_NODES * HEADS * 4);
    float* al1d  = (float*)carve((size_t)N_NODES * HEADS * 4);
    int* counts  = (int*)carve((size_t)N_NODES * 4);
    int* cursor  = (int*)carve((size_t)N_NODES * 4);
    int* offsets = (int*)carve((size_t)(N_NODES + 1) * 4);
    int* esrc    = (int*)carve((size_t)NEDGE * 4);
    float* ew    = (float*)carve((size_t)NEDGE * HEADS * 4);
    float* wself = (float*)carve((size_t)N_NODES * HEADS * 4);
    unsigned short* x2b = (unsigned short*)carve((size_t)N_NODES * HH * 2);
    float* h2    = (float*)carve((size_t)N_NODES * NCLS * 4);
    float* al2s  = (float*)carve((size_t)N_NODES * 4);
    float* al2d  = (float*)carve((size_t)N_NODES * 4);
    float* ew2   = (float*)carve((size_t)NEDGE * 4);
    float* wself2= (float*)carve((size_t)N_NODES * 4);
    if ((size_t)(p - (char*)d_ws) > ws_size) return;  // workspace too small

    hipMemsetAsync(counts, 0, N_NODES * 4, stream);
    hipMemsetAsync(cursor, 0, N_NODES * 4, stream);

    cvt_f32_bf16<<<2048, 256, 0, stream>>>(x, xb, N_NODES * F_INK);
    cvt_w1t<<<(F_INK * HH + 255) / 256, 256, 0, stream>>>(W1, w1t);
    cvt_w2t<<<(HH * NCLS + 255) / 256, 256, 0, stream>>>(W2, w2t);
    count_edges<<<(NEDGE + 255) / 256, 256, 0, stream>>>(dst, counts);
    scan_offsets<<<1, 1024, 0, stream>>>(counts, offsets);
    scatter_edges<<<(NEDGE + 255) / 256, 256, 0, stream>>>(src, dst, offsets, cursor, esrc);
    gemm1<<<(N_NODES / 16 + 3) / 4, 256, 0, stream>>>(xb, w1t, h1b);
    attn1_dots<<<(N_NODES + 3) / 4, 256, 0, stream>>>(h1b, as1, ad1, al1s, al1d);
    softmax1<<<(N_NODES + 3) / 4, 256, 0, stream>>>(al1s, al1d, offsets, esrc, ew, wself);
    agg1<<<N_NODES, 256, 0, stream>>>(h1b, ew, wself, offsets, esrc, b1, x2b);
    gemm2<<<(N_NODES / 16 + 3) / 4, 256, 0, stream>>>(x2b, w2t, as2, ad2, h2, al2s, al2d);
    softmax2<<<(N_NODES + 3) / 4, 256, 0, stream>>>(al2s, al2d, offsets, esrc, ew2, wself2);
    agg2<<<(N_NODES + 3) / 4, 256, 0, stream>>>(h2, ew2, wself2, offsets, esrc, b2, out);
}

// Round 4
// 370.059 us; speedup vs baseline: 1.8906x; 1.2233x over previous
//
#include <hip/hip_runtime.h>
#include <hip/hip_bf16.h>
#include <math.h>

#define N_NODES 50000
#define F_INK   256
#define HEADS   8
#define HID     64
#define HH      512     // HEADS*HID
#define NCLS    16
#define NEDGE   400000
#define NEG_SLOPE 0.2f

#define BCOLS 64
#define KPAD  264       // 256 + 8 bf16 pad -> optimal quad-bank spread

typedef __attribute__((ext_vector_type(8))) short short8;
typedef __attribute__((ext_vector_type(4))) float float4v;

__device__ __forceinline__ float bf2f(unsigned short u){
    unsigned int x = ((unsigned int)u) << 16;
    float f; __builtin_memcpy(&f, &x, 4); return f;
}
__device__ __forceinline__ unsigned short f2bf(float f){
    unsigned int x; __builtin_memcpy(&x, &f, 4);
    unsigned int r = x + 0x7FFFu + ((x >> 16) & 1u);   // RNE
    return (unsigned short)(r >> 16);
}
__device__ __forceinline__ float lrelu(float a){ return a > 0.f ? a : NEG_SLOPE * a; }

// ---------------- conversions ----------------
__global__ void cvt_f32_bf16(const float* __restrict__ in, unsigned short* __restrict__ out, int n){
    int i = blockIdx.x * blockDim.x + threadIdx.x;
    int stride = gridDim.x * blockDim.x;
    for (; i < n; i += stride) out[i] = f2bf(in[i]);
}

// W1 [256][512] fp32 -> W1T [512][256] bf16
__global__ void cvt_w1t(const float* __restrict__ W1, unsigned short* __restrict__ W1T){
    int i = blockIdx.x * blockDim.x + threadIdx.x;
    if (i >= F_INK * HH) return;
    int k = i / HH, c = i % HH;
    W1T[c * F_INK + k] = f2bf(W1[i]);
}

// W2 [512][16] fp32 -> W2T [16][512] bf16
__global__ void cvt_w2t(const float* __restrict__ W2, unsigned short* __restrict__ W2T){
    int i = blockIdx.x * blockDim.x + threadIdx.x;
    if (i >= HH * NCLS) return;
    int k = i / NCLS, c = i % NCLS;
    W2T[c * HH + k] = f2bf(W2[i]);
}

// ---------------- CSR build ----------------
__global__ void count_edges(const int* __restrict__ dst, int* __restrict__ counts){
    int e = blockIdx.x * blockDim.x + threadIdx.x;
    if (e < NEDGE) atomicAdd(&counts[dst[e]], 1);
}

__global__ void scan_offsets(const int* __restrict__ counts, int* __restrict__ offsets){
    __shared__ int tsum[1024];
    int t = threadIdx.x;
    const int per = (N_NODES + 1023) / 1024;
    int begin = t * per;
    int end = begin + per; if (end > N_NODES) end = N_NODES;
    int s = 0;
    if (begin < N_NODES) for (int i = begin; i < end; i++) s += counts[i];
    tsum[t] = s; __syncthreads();
    int val = s;
    for (int off = 1; off < 1024; off <<= 1){
        int v2 = (t >= off) ? tsum[t - off] : 0;
        __syncthreads();
        val += v2; tsum[t] = val;
        __syncthreads();
    }
    int run = val - s;
    if (begin < N_NODES) for (int i = begin; i < end; i++){ offsets[i] = run; run += counts[i]; }
    if (t == 0) offsets[N_NODES] = tsum[1023];
}

__global__ void scatter_edges(const int* __restrict__ src, const int* __restrict__ dst,
                              const int* __restrict__ offsets, int* __restrict__ cursor,
                              int* __restrict__ esrc){
    int e = blockIdx.x * blockDim.x + threadIdx.x;
    if (e < NEDGE){
        int d = dst[e];
        int pos = offsets[d] + atomicAdd(&cursor[d], 1);
        esrc[pos] = src[e];
    }
}

// ---------------- GEMM1: h1 = bf16(x) @ bf16(W1), output bf16 [N][512] ----------------
// Each block owns a 64-col panel of W1T, LDS-resident (padded); grid-strides 64-row chunks.
__global__ __launch_bounds__(256) void gemm1(const unsigned short* __restrict__ xb,
                                             const unsigned short* __restrict__ w1t,
                                             unsigned short* __restrict__ h1b){
    __shared__ unsigned short bs[BCOLS * KPAD];   // 33 KB
    int cb  = blockIdx.x & 7;          // col panel: cols [cb*64, cb*64+64)
    int rg  = blockIdx.x >> 3;
    int nrg = gridDim.x >> 3;
    {   // stage B panel once
        int kc = threadIdx.x & 31;     // k-chunk of 8
        int c0 = threadIdx.x >> 5;     // 0..7
#pragma unroll
        for (int it = 0; it < 8; it++){
            int col = it * 8 + c0;
            short8 v = *(const short8*)(w1t + (size_t)(cb * BCOLS + col) * F_INK + kc * 8);
            *(short8*)(&bs[col * KPAD + kc * 8]) = v;
        }
    }
    __syncthreads();
    int w    = threadIdx.x >> 6;
    int lane = threadIdx.x & 63;
    int lr = lane & 15, lk = lane >> 4;
    const int nchunk = (N_NODES + 63) / 64;       // 782
    for (int ch = rg; ch < nchunk; ch += nrg){
        int rowbase = ch * 64 + w * 16;
        if (rowbase >= N_NODES) continue;         // 50000 % 16 == 0, tiles never straddle
        short8 a[8];
#pragma unroll
        for (int ks = 0; ks < 8; ks++)
            a[ks] = *(const short8*)(xb + (size_t)(rowbase + lr) * F_INK + ks * 32 + lk * 8);
#pragma unroll
        for (int ct = 0; ct < 4; ct++){
            float4v acc = {0.f, 0.f, 0.f, 0.f};
#pragma unroll
            for (int ks = 0; ks < 8; ks++){
                short8 b = *(const short8*)(&bs[(ct * 16 + lr) * KPAD + ks * 32 + lk * 8]);
                acc = __builtin_amdgcn_mfma_f32_16x16x32_bf16(a[ks], b, acc, 0, 0, 0);
            }
#pragma unroll
            for (int r = 0; r < 4; r++)
                h1b[(size_t)(rowbase + lk * 4 + r) * HH + cb * BCOLS + ct * 16 + lr] = f2bf(acc[r]);
        }
    }
}

// ---------------- attention dots: al_src/al_dst [N][8] ----------------
__global__ __launch_bounds__(256) void attn1_dots(const unsigned short* __restrict__ h1b,
        const float* __restrict__ a_src, const float* __restrict__ a_dst,
        float* __restrict__ al_s, float* __restrict__ al_d){
    int n = blockIdx.x * 4 + (threadIdx.x >> 6);
    int lane = threadIdx.x & 63;
    if (n >= N_NODES) return;
    short8 v = *(const short8*)(h1b + (size_t)n * HH + lane * 8);
    int head = lane >> 3;
    int j0 = (lane & 7) * 8;
    float ps = 0.f, pd = 0.f;
#pragma unroll
    for (int j = 0; j < 8; j++){
        float hv = bf2f((unsigned short)v[j]);
        ps += hv * a_src[head * HID + j0 + j];
        pd += hv * a_dst[head * HID + j0 + j];
    }
#pragma unroll
    for (int off = 1; off < 8; off <<= 1){
        ps += __shfl_xor(ps, off);
        pd += __shfl_xor(pd, off);
    }
    if ((lane & 7) == 0){
        al_s[n * HEADS + head] = ps;
        al_d[n * HEADS + head] = pd;
    }
}

// ---------------- layer-1 softmax weights: ew[p][8], wself[d][8] ----------------
__global__ __launch_bounds__(256) void softmax1(
        const float* __restrict__ al_s, const float* __restrict__ al_d,
        const int* __restrict__ offsets, const int* __restrict__ esrc,
        float* __restrict__ ew, float* __restrict__ wself){
    int d = blockIdx.x * 4 + (threadIdx.x >> 6);
    int lane = threadIdx.x & 63;
    if (d >= N_NODES) return;
    int h = lane & 7, i = lane >> 3;
    int off = offsets[d], deg = offsets[d + 1] - off;
    float ald = al_d[d * HEADS + h];
    float aself = lrelu(al_s[d * HEADS + h] + ald);
    float m = aself;
    for (int base = 0; base < deg; base += 8){
        int e = base + i;
        float a = -1e30f;
        if (e < deg) a = lrelu(al_s[esrc[off + e] * HEADS + h] + ald);
        a = fmaxf(a, __shfl_xor(a, 8));
        a = fmaxf(a, __shfl_xor(a, 16));
        a = fmaxf(a, __shfl_xor(a, 32));
        m = fmaxf(m, a);
    }
    float denom = __expf(aself - m);
    for (int base = 0; base < deg; base += 8){
        int e = base + i;
        float w = 0.f;
        if (e < deg){
            w = __expf(lrelu(al_s[esrc[off + e] * HEADS + h] + ald) - m);
            ew[(size_t)(off + e) * HEADS + h] = w;
        }
        float ws = w;
        ws += __shfl_xor(ws, 8);
        ws += __shfl_xor(ws, 16);
        ws += __shfl_xor(ws, 32);
        denom += ws;
    }
    float inv = 1.f / denom;
    if (i == 0) wself[d * HEADS + h] = __expf(aself - m) * inv;
    for (int base = 0; base < deg; base += 8){
        int e = base + i;
        if (e < deg) ew[(size_t)(off + e) * HEADS + h] *= inv;
    }
}

// ---------------- layer-1 aggregation (precomputed weights) + elu -> x2b ----------------
__global__ __launch_bounds__(256) void agg1(const unsigned short* __restrict__ h1b,
        const float* __restrict__ ew, const float* __restrict__ wself,
        const int* __restrict__ offsets, const int* __restrict__ esrc,
        const float* __restrict__ b1, unsigned short* __restrict__ x2b){
    __shared__ int   s_src[32];
    __shared__ float s_w[32][HEADS];
    int d = blockIdx.x;
    int g  = threadIdx.x >> 5;
    int sl = threadIdx.x & 31;
    int off = offsets[d], deg = offsets[d + 1] - off;
    float w0 = wself[d * HEADS + g];
    unsigned int pv = *(const unsigned int*)(h1b + (size_t)d * HH + g * HID + sl * 2);
    float acc0 = w0 * bf2f((unsigned short)(pv & 0xffff));
    float acc1 = w0 * bf2f((unsigned short)(pv >> 16));
    for (int base = 0; base < deg; base += 32){
        int m2 = deg - base; if (m2 > 32) m2 = 32;
        __syncthreads();
        if (threadIdx.x < m2) s_src[threadIdx.x] = esrc[off + base + threadIdx.x];
        {
            int k = threadIdx.x >> 3, j = threadIdx.x & 7;
            if (k < m2) s_w[k][j] = ew[(size_t)(off + base + k) * HEADS + j];
        }
        __syncthreads();
        for (int i2 = 0; i2 < m2; i2++){
            int s = s_src[i2];
            float w = s_w[i2][g];
            unsigned int p2 = *(const unsigned int*)(h1b + (size_t)s * HH + g * HID + sl * 2);
            acc0 += w * bf2f((unsigned short)(p2 & 0xffff));
            acc1 += w * bf2f((unsigned short)(p2 >> 16));
        }
    }
    float v0 = acc0 + b1[g * HID + sl * 2];
    float v1 = acc1 + b1[g * HID + sl * 2 + 1];
    v0 = v0 > 0.f ? v0 : __expf(v0) - 1.f;   // elu
    v1 = v1 > 0.f ? v1 : __expf(v1) - 1.f;
    unsigned int o = ((unsigned int)f2bf(v1) << 16) | f2bf(v0);
    *(unsigned int*)(x2b + (size_t)d * HH + g * HID + sl * 2) = o;
}

// ---------------- layer-2 GEMM via MFMA: h2 = x2b @ W2 (+ fused attention dots) --------
__global__ __launch_bounds__(256) void gemm2(const unsigned short* __restrict__ x2b,
        const unsigned short* __restrict__ w2t,
        const float* __restrict__ a_s2, const float* __restrict__ a_d2,
        float* __restrict__ h2, float* __restrict__ al2s, float* __restrict__ al2d){
    int wave = (blockIdx.x * blockDim.x + threadIdx.x) >> 6;
    int lane = threadIdx.x & 63;
    if (wave >= N_NODES / 16) return;
    int rowbase = wave * 16;
    int lr = lane & 15, lk = lane >> 4;
    float4v acc = {0.f, 0.f, 0.f, 0.f};
#pragma unroll
    for (int ks = 0; ks < 16; ks++){
        short8 a = *(const short8*)(x2b + (size_t)(rowbase + lr) * HH + ks * 32 + lk * 8);
        short8 b = *(const short8*)(w2t + (size_t)lr * HH + ks * 32 + lk * 8);
        acc = __builtin_amdgcn_mfma_f32_16x16x32_bf16(a, b, acc, 0, 0, 0);
    }
#pragma unroll
    for (int r = 0; r < 4; r++)
        h2[(size_t)(rowbase + lk * 4 + r) * NCLS + lr] = acc[r];
    float s_a = a_s2[lr], d_a = a_d2[lr];
#pragma unroll
    for (int r = 0; r < 4; r++){
        float ps = acc[r] * s_a, pd = acc[r] * d_a;
#pragma unroll
        for (int off = 1; off < 16; off <<= 1){
            ps += __shfl_xor(ps, off);
            pd += __shfl_xor(pd, off);
        }
        if (lr == 0){
            al2s[rowbase + lk * 4 + r] = ps;
            al2d[rowbase + lk * 4 + r] = pd;
        }
    }
}

// ---------------- layer-2 softmax weights ----------------
__global__ __launch_bounds__(256) void softmax2(
        const float* __restrict__ al2s, const float* __restrict__ al2d,
        const int* __restrict__ offsets, const int* __restrict__ esrc,
        float* __restrict__ ew2, float* __restrict__ wself2){
    int d = blockIdx.x * 4 + (threadIdx.x >> 6);
    int lane = threadIdx.x & 63;
    if (d >= N_NODES) return;
    int off = offsets[d], deg = offsets[d + 1] - off;
    float ald = al2d[d];
    float aself = lrelu(al2s[d] + ald);
    float m = aself;
    for (int base = 0; base < deg; base += 64){
        int e = base + lane;
        float a = (e < deg) ? lrelu(al2s[esrc[off + e]] + ald) : -1e30f;
#pragma unroll
        for (int o = 1; o < 64; o <<= 1) a = fmaxf(a, __shfl_xor(a, o));
        m = fmaxf(m, a);
    }
    float denom = __expf(aself - m);
    for (int base = 0; base < deg; base += 64){
        int e = base + lane;
        float w = 0.f;
        if (e < deg){
            w = __expf(lrelu(al2s[esrc[off + e]] + ald) - m);
            ew2[off + e] = w;
        }
#pragma unroll
        for (int o = 1; o < 64; o <<= 1) w += __shfl_xor(w, o);
        denom += w;
    }
    float inv = 1.f / denom;
    if (lane == 0) wself2[d] = __expf(aself - m) * inv;
    for (int base = 0; base < deg; base += 64){
        int e = base + lane;
        if (e < deg) ew2[off + e] *= inv;
    }
}

// ---------------- layer-2 aggregation -> out [N][16] fp32 ----------------
__global__ __launch_bounds__(256) void agg2(const float* __restrict__ h2,
        const float* __restrict__ ew2, const float* __restrict__ wself2,
        const int* __restrict__ offsets, const int* __restrict__ esrc,
        const float* __restrict__ b2, float* __restrict__ out){
    int d = blockIdx.x * 4 + (threadIdx.x >> 6);
    int lane = threadIdx.x & 63;
    if (d >= N_NODES) return;
    int off = offsets[d], deg = offsets[d + 1] - off;
    int sg = lane >> 4, col = lane & 15;
    float acc = (sg == 0) ? wself2[d] * h2[(size_t)d * NCLS + col] : 0.f;
    for (int base = 0; base < deg; base += 4){
        int i = base + sg;
        if (i < deg){
            int s = esrc[off + i];
            acc += ew2[off + i] * h2[(size_t)s * NCLS + col];
        }
    }
    acc += __shfl_xor(acc, 16);
    acc += __shfl_xor(acc, 32);
    if (lane < NCLS) out[(size_t)d * NCLS + lane] = acc + b2[lane];
}

extern "C" void kernel_launch(void* const* d_in, const int* in_sizes, int n_in,
                              void* d_out, int out_size, void* d_ws, size_t ws_size,
                              hipStream_t stream){
    const float* x   = (const float*)d_in[0];
    const int*   ei  = (const int*)d_in[1];
    const int*   src = ei;
    const int*   dst = ei + NEDGE;
    const float* W1  = (const float*)d_in[2];
    const float* as1 = (const float*)d_in[3];
    const float* ad1 = (const float*)d_in[4];
    const float* b1  = (const float*)d_in[5];
    const float* W2  = (const float*)d_in[6];
    const float* as2 = (const float*)d_in[7];
    const float* ad2 = (const float*)d_in[8];
    const float* b2  = (const float*)d_in[9];
    float* out = (float*)d_out;

    char* p = (char*)d_ws;
    auto carve = [&](size_t bytes) -> char* {
        char* r = p; p += (bytes + 255) & ~(size_t)255; return r;
    };
    unsigned short* xb   = (unsigned short*)carve((size_t)N_NODES * F_INK * 2);
    unsigned short* w1t  = (unsigned short*)carve((size_t)HH * F_INK * 2);
    unsigned short* w2t  = (unsigned short*)carve((size_t)HH * NCLS * 2);
    unsigned short* h1b  = (unsigned short*)carve((size_t)N_NODES * HH * 2);
    float* al1s  = (float*)carve((size_t)N_NODES * HEADS * 4);
    float* al1d  = (float*)carve((size_t)N_NODES * HEADS * 4);
    int* counts  = (int*)carve((size_t)N_NODES * 4);
    int* cursor  = (int*)carve((size_t)N_NODES * 4);
    int* offsets = (int*)carve((size_t)(N_NODES + 1) * 4);
    int* esrc    = (int*)carve((size_t)NEDGE * 4);
    float* ew    = (float*)carve((size_t)NEDGE * HEADS * 4);
    float* wself = (float*)carve((size_t)N_NODES * HEADS * 4);
    unsigned short* x2b = (unsigned short*)carve((size_t)N_NODES * HH * 2);
    float* h2    = (float*)carve((size_t)N_NODES * NCLS * 4);
    float* al2s  = (float*)carve((size_t)N_NODES * 4);
    float* al2d  = (float*)carve((size_t)N_NODES * 4);
    float* ew2   = (float*)carve((size_t)NEDGE * 4);
    float* wself2= (float*)carve((size_t)N_NODES * 4);
    if ((size_t)(p - (char*)d_ws) > ws_size) return;  // workspace too small

    hipMemsetAsync(counts, 0, N_NODES * 4, stream);
    hipMemsetAsync(cursor, 0, N_NODES * 4, stream);

    cvt_f32_bf16<<<2048, 256, 0, stream>>>(x, xb, N_NODES * F_INK);
    cvt_w1t<<<(F_INK * HH + 255) / 256, 256, 0, stream>>>(W1, w1t);
    cvt_w2t<<<(HH * NCLS + 255) / 256, 256, 0, stream>>>(W2, w2t);
    count_edges<<<(NEDGE + 255) / 256, 256, 0, stream>>>(dst, counts);
    scan_offsets<<<1, 1024, 0, stream>>>(counts, offsets);
    scatter_edges<<<(NEDGE + 255) / 256, 256, 0, stream>>>(src, dst, offsets, cursor, esrc);
    gemm1<<<8 * 128, 256, 0, stream>>>(xb, w1t, h1b);
    attn1_dots<<<(N_NODES + 3) / 4, 256, 0, stream>>>(h1b, as1, ad1, al1s, al1d);
    softmax1<<<(N_NODES + 3) / 4, 256, 0, stream>>>(al1s, al1d, offsets, esrc, ew, wself);
    agg1<<<N_NODES, 256, 0, stream>>>(h1b, ew, wself, offsets, esrc, b1, x2b);
    gemm2<<<(N_NODES / 16 + 3) / 4, 256, 0, stream>>>(x2b, w2t, as2, ad2, h2, al2s, al2d);
    softmax2<<<(N_NODES + 3) / 4, 256, 0, stream>>>(al2s, al2d, offsets, esrc, ew2, wself2);
    agg2<<<(N_NODES + 3) / 4, 256, 0, stream>>>(h2, ew2, wself2, offsets, esrc, b2, out);
}

// Round 6
// 347.355 us; speedup vs baseline: 2.0142x; 1.0654x over previous
//
#include <hip/hip_runtime.h>
#include <hip/hip_bf16.h>
#include <math.h>

#define N_NODES 50000
#define F_INK   256
#define HEADS   8
#define HID     64
#define HH      512     // HEADS*HID
#define NCLS    16
#define NEDGE   400000
#define NEG_SLOPE 0.2f

#define BCOLS 64
#define KPAD  264       // 256 + 8 bf16 pad -> optimal quad-bank spread

typedef __attribute__((ext_vector_type(8))) short short8;
typedef __attribute__((ext_vector_type(4))) short sh4;
typedef __attribute__((ext_vector_type(4))) float float4v;

__device__ __forceinline__ float bf2f(unsigned short u){
    unsigned int x = ((unsigned int)u) << 16;
    float f; __builtin_memcpy(&f, &x, 4); return f;
}
__device__ __forceinline__ unsigned short f2bf(float f){
    unsigned int x; __builtin_memcpy(&x, &f, 4);
    unsigned int r = x + 0x7FFFu + ((x >> 16) & 1u);   // RNE
    return (unsigned short)(r >> 16);
}
__device__ __forceinline__ float lrelu(float a){ return a > 0.f ? a : NEG_SLOPE * a; }

// ---------------- conversions ----------------
__global__ void cvt_f32_bf16(const float* __restrict__ in, unsigned short* __restrict__ out, int n4){
    int i = blockIdx.x * blockDim.x + threadIdx.x;
    int stride = gridDim.x * blockDim.x;
    for (; i < n4; i += stride){
        float4v f = *(const float4v*)(in + (size_t)i * 4);
        sh4 o;
#pragma unroll
        for (int j = 0; j < 4; j++) o[j] = (short)f2bf(f[j]);
        *(sh4*)(out + (size_t)i * 4) = o;
    }
}

// W1 [256][512] fp32 -> W1T [512][256] bf16
__global__ void cvt_w1t(const float* __restrict__ W1, unsigned short* __restrict__ W1T){
    int i = blockIdx.x * blockDim.x + threadIdx.x;
    if (i >= F_INK * HH) return;
    int k = i / HH, c = i % HH;
    W1T[c * F_INK + k] = f2bf(W1[i]);
}

// W2 [512][16] fp32 -> W2T [16][512] bf16
__global__ void cvt_w2t(const float* __restrict__ W2, unsigned short* __restrict__ W2T){
    int i = blockIdx.x * blockDim.x + threadIdx.x;
    if (i >= HH * NCLS) return;
    int k = i / NCLS, c = i % NCLS;
    W2T[c * HH + k] = f2bf(W2[i]);
}

// ---------------- CSR build ----------------
__global__ void count_edges(const int* __restrict__ dst, int* __restrict__ counts){
    int e = blockIdx.x * blockDim.x + threadIdx.x;
    if (e < NEDGE) atomicAdd(&counts[dst[e]], 1);
}

__global__ void scan_offsets(const int* __restrict__ counts, int* __restrict__ offsets){
    __shared__ int tsum[1024];
    int t = threadIdx.x;
    const int per = (N_NODES + 1023) / 1024;
    int begin = t * per;
    int end = begin + per; if (end > N_NODES) end = N_NODES;
    int s = 0;
    if (begin < N_NODES) for (int i = begin; i < end; i++) s += counts[i];
    tsum[t] = s; __syncthreads();
    int val = s;
    for (int off = 1; off < 1024; off <<= 1){
        int v2 = (t >= off) ? tsum[t - off] : 0;
        __syncthreads();
        val += v2; tsum[t] = val;
        __syncthreads();
    }
    int run = val - s;
    if (begin < N_NODES) for (int i = begin; i < end; i++){ offsets[i] = run; run += counts[i]; }
    if (t == 0) offsets[N_NODES] = tsum[1023];
}

__global__ void scatter_edges(const int* __restrict__ src, const int* __restrict__ dst,
                              const int* __restrict__ offsets, int* __restrict__ cursor,
                              int* __restrict__ esrc){
    int e = blockIdx.x * blockDim.x + threadIdx.x;
    if (e < NEDGE){
        int d = dst[e];
        int pos = offsets[d] + atomicAdd(&cursor[d], 1);
        esrc[pos] = src[e];
    }
}

// ---------------- GEMM1: h1 = bf16(x) @ bf16(W1), output bf16 [N][512] ----------------
__global__ __launch_bounds__(256) void gemm1(const unsigned short* __restrict__ xb,
                                             const unsigned short* __restrict__ w1t,
                                             unsigned short* __restrict__ h1b){
    __shared__ unsigned short bs[BCOLS * KPAD];   // 33 KB
    int cb  = blockIdx.x & 7;          // col panel: cols [cb*64, cb*64+64)
    int rg  = blockIdx.x >> 3;
    int nrg = gridDim.x >> 3;
    {   // stage B panel once
        int kc = threadIdx.x & 31;     // k-chunk of 8
        int c0 = threadIdx.x >> 5;     // 0..7
#pragma unroll
        for (int it = 0; it < 8; it++){
            int col = it * 8 + c0;
            short8 v = *(const short8*)(w1t + (size_t)(cb * BCOLS + col) * F_INK + kc * 8);
            *(short8*)(&bs[col * KPAD + kc * 8]) = v;
        }
    }
    __syncthreads();
    int w    = threadIdx.x >> 6;
    int lane = threadIdx.x & 63;
    int lr = lane & 15, lk = lane >> 4;
    const int nchunk = (N_NODES + 63) / 64;       // 782
    for (int ch = rg; ch < nchunk; ch += nrg){
        int rowbase = ch * 64 + w * 16;
        if (rowbase >= N_NODES) continue;
        short8 a[8];
#pragma unroll
        for (int ks = 0; ks < 8; ks++)
            a[ks] = *(const short8*)(xb + (size_t)(rowbase + lr) * F_INK + ks * 32 + lk * 8);
#pragma unroll
        for (int ct = 0; ct < 4; ct++){
            float4v acc = {0.f, 0.f, 0.f, 0.f};
#pragma unroll
            for (int ks = 0; ks < 8; ks++){
                short8 b = *(const short8*)(&bs[(ct * 16 + lr) * KPAD + ks * 32 + lk * 8]);
                acc = __builtin_amdgcn_mfma_f32_16x16x32_bf16(a[ks], b, acc, 0, 0, 0);
            }
#pragma unroll
            for (int r = 0; r < 4; r++)
                h1b[(size_t)(rowbase + lk * 4 + r) * HH + cb * BCOLS + ct * 16 + lr] = f2bf(acc[r]);
        }
    }
}

// ---------------- attention dots: al_src/al_dst [N][8] ----------------
__global__ __launch_bounds__(256) void attn1_dots(const unsigned short* __restrict__ h1b,
        const float* __restrict__ a_src, const float* __restrict__ a_dst,
        float* __restrict__ al_s, float* __restrict__ al_d){
    int n = blockIdx.x * 4 + (threadIdx.x >> 6);
    int lane = threadIdx.x & 63;
    if (n >= N_NODES) return;
    short8 v = *(const short8*)(h1b + (size_t)n * HH + lane * 8);
    int head = lane >> 3;
    int j0 = (lane & 7) * 8;
    float ps = 0.f, pd = 0.f;
#pragma unroll
    for (int j = 0; j < 8; j++){
        float hv = bf2f((unsigned short)v[j]);
        ps += hv * a_src[head * HID + j0 + j];
        pd += hv * a_dst[head * HID + j0 + j];
    }
#pragma unroll
    for (int off = 1; off < 8; off <<= 1){
        ps += __shfl_xor(ps, off);
        pd += __shfl_xor(pd, off);
    }
    if ((lane & 7) == 0){
        al_s[n * HEADS + head] = ps;
        al_d[n * HEADS + head] = pd;
    }
}

// ---------------- layer-1 softmax weights: ew[p][8], wself[d][8] ----------------
__global__ __launch_bounds__(256) void softmax1(
        const float* __restrict__ al_s, const float* __restrict__ al_d,
        const int* __restrict__ offsets, const int* __restrict__ esrc,
        float* __restrict__ ew, float* __restrict__ wself){
    int d = blockIdx.x * 4 + (threadIdx.x >> 6);
    int lane = threadIdx.x & 63;
    if (d >= N_NODES) return;
    int h = lane & 7, i = lane >> 3;
    int off = offsets[d], deg = offsets[d + 1] - off;
    float ald = al_d[d * HEADS + h];
    float aself = lrelu(al_s[d * HEADS + h] + ald);
    float m = aself;
    for (int base = 0; base < deg; base += 8){
        int e = base + i;
        float a = -1e30f;
        if (e < deg) a = lrelu(al_s[esrc[off + e] * HEADS + h] + ald);
        a = fmaxf(a, __shfl_xor(a, 8));
        a = fmaxf(a, __shfl_xor(a, 16));
        a = fmaxf(a, __shfl_xor(a, 32));
        m = fmaxf(m, a);
    }
    float denom = __expf(aself - m);
    for (int base = 0; base < deg; base += 8){
        int e = base + i;
        float w = 0.f;
        if (e < deg){
            w = __expf(lrelu(al_s[esrc[off + e] * HEADS + h] + ald) - m);
            ew[(size_t)(off + e) * HEADS + h] = w;
        }
        float ws = w;
        ws += __shfl_xor(ws, 8);
        ws += __shfl_xor(ws, 16);
        ws += __shfl_xor(ws, 32);
        denom += ws;
    }
    float inv = 1.f / denom;
    if (i == 0) wself[d * HEADS + h] = __expf(aself - m) * inv;
    for (int base = 0; base < deg; base += 8){
        int e = base + i;
        if (e < deg) ew[(size_t)(off + e) * HEADS + h] *= inv;
    }
}

// ---------------- layer-1 aggregation (wave-per-edge-subset) + elu -> x2b ----------------
// block = 1 dst, 4 waves; wave w owns edges w, w+4, ... ; lane covers 8 cols (16B load);
// 2-deep manual unroll; cross-wave combine via 8KB LDS.
__global__ __launch_bounds__(256) void agg1(const unsigned short* __restrict__ h1b,
        const float* __restrict__ ew, const float* __restrict__ wself,
        const int* __restrict__ offsets, const int* __restrict__ esrc,
        const float* __restrict__ b1, unsigned short* __restrict__ x2b){
    __shared__ float s_red[4][HH];    // 8 KB
    int d = blockIdx.x;
    int w = threadIdx.x >> 6;
    int lane = threadIdx.x & 63;
    int g = lane >> 3;                 // head
    int c0 = (lane & 7) * 8;           // col base within head
    int off = offsets[d], deg = offsets[d + 1] - off;
    float acc[8];
#pragma unroll
    for (int j = 0; j < 8; j++) acc[j] = 0.f;
    if (w == 0){                       // self edge
        float w0 = wself[d * HEADS + g];
        short8 v = *(const short8*)(h1b + (size_t)d * HH + g * HID + c0);
#pragma unroll
        for (int j = 0; j < 8; j++) acc[j] += w0 * bf2f((unsigned short)v[j]);
    }
    int e = w;
    for (; e + 4 < deg; e += 8){       // two edges in flight
        int s0 = esrc[off + e], s1 = esrc[off + e + 4];
        float w0 = ew[(size_t)(off + e) * HEADS + g];
        float w1 = ew[(size_t)(off + e + 4) * HEADS + g];
        short8 v0 = *(const short8*)(h1b + (size_t)s0 * HH + g * HID + c0);
        short8 v1 = *(const short8*)(h1b + (size_t)s1 * HH + g * HID + c0);
#pragma unroll
        for (int j = 0; j < 8; j++) acc[j] += w0 * bf2f((unsigned short)v0[j]);
#pragma unroll
        for (int j = 0; j < 8; j++) acc[j] += w1 * bf2f((unsigned short)v1[j]);
    }
    if (e < deg){
        int s0 = esrc[off + e];
        float w0 = ew[(size_t)(off + e) * HEADS + g];
        short8 v0 = *(const short8*)(h1b + (size_t)s0 * HH + g * HID + c0);
#pragma unroll
        for (int j = 0; j < 8; j++) acc[j] += w0 * bf2f((unsigned short)v0[j]);
    }
#pragma unroll
    for (int j = 0; j < 8; j++) s_red[w][g * HID + c0 + j] = acc[j];
    __syncthreads();
    int col = threadIdx.x * 2;
    float v0 = s_red[0][col] + s_red[1][col] + s_red[2][col] + s_red[3][col] + b1[col];
    float v1 = s_red[0][col+1] + s_red[1][col+1] + s_red[2][col+1] + s_red[3][col+1] + b1[col+1];
    v0 = v0 > 0.f ? v0 : __expf(v0) - 1.f;   // elu
    v1 = v1 > 0.f ? v1 : __expf(v1) - 1.f;
    unsigned int o = ((unsigned int)f2bf(v1) << 16) | f2bf(v0);
    *(unsigned int*)(x2b + (size_t)d * HH + col) = o;
}

// ---------------- layer-2 GEMM via MFMA: h2 = x2b @ W2 (+ fused attention dots) --------
__global__ __launch_bounds__(256) void gemm2(const unsigned short* __restrict__ x2b,
        const unsigned short* __restrict__ w2t,
        const float* __restrict__ a_s2, const float* __restrict__ a_d2,
        float* __restrict__ h2, float* __restrict__ al2s, float* __restrict__ al2d){
    int wave = (blockIdx.x * blockDim.x + threadIdx.x) >> 6;
    int lane = threadIdx.x & 63;
    if (wave >= N_NODES / 16) return;
    int rowbase = wave * 16;
    int lr = lane & 15, lk = lane >> 4;
    float4v acc = {0.f, 0.f, 0.f, 0.f};
#pragma unroll
    for (int ks = 0; ks < 16; ks++){
        short8 a = *(const short8*)(x2b + (size_t)(rowbase + lr) * HH + ks * 32 + lk * 8);
        short8 b = *(const short8*)(w2t + (size_t)lr * HH + ks * 32 + lk * 8);
        acc = __builtin_amdgcn_mfma_f32_16x16x32_bf16(a, b, acc, 0, 0, 0);
    }
#pragma unroll
    for (int r = 0; r < 4; r++)
        h2[(size_t)(rowbase + lk * 4 + r) * NCLS + lr] = acc[r];
    float s_a = a_s2[lr], d_a = a_d2[lr];
#pragma unroll
    for (int r = 0; r < 4; r++){
        float ps = acc[r] * s_a, pd = acc[r] * d_a;
#pragma unroll
        for (int off = 1; off < 16; off <<= 1){
            ps += __shfl_xor(ps, off);
            pd += __shfl_xor(pd, off);
        }
        if (lr == 0){
            al2s[rowbase + lk * 4 + r] = ps;
            al2d[rowbase + lk * 4 + r] = pd;
        }
    }
}

// ---------------- layer-2 softmax weights ----------------
__global__ __launch_bounds__(256) void softmax2(
        const float* __restrict__ al2s, const float* __restrict__ al2d,
        const int* __restrict__ offsets, const int* __restrict__ esrc,
        float* __restrict__ ew2, float* __restrict__ wself2){
    int d = blockIdx.x * 4 + (threadIdx.x >> 6);
    int lane = threadIdx.x & 63;
    if (d >= N_NODES) return;
    int off = offsets[d], deg = offsets[d + 1] - off;
    float ald = al2d[d];
    float aself = lrelu(al2s[d] + ald);
    float m = aself;
    for (int base = 0; base < deg; base += 64){
        int e = base + lane;
        float a = (e < deg) ? lrelu(al2s[esrc[off + e]] + ald) : -1e30f;
#pragma unroll
        for (int o = 1; o < 64; o <<= 1) a = fmaxf(a, __shfl_xor(a, o));
        m = fmaxf(m, a);
    }
    float denom = __expf(aself - m);
    for (int base = 0; base < deg; base += 64){
        int e = base + lane;
        float w = 0.f;
        if (e < deg){
            w = __expf(lrelu(al2s[esrc[off + e]] + ald) - m);
            ew2[off + e] = w;
        }
#pragma unroll
        for (int o = 1; o < 64; o <<= 1) w += __shfl_xor(w, o);
        denom += w;
    }
    float inv = 1.f / denom;
    if (lane == 0) wself2[d] = __expf(aself - m) * inv;
    for (int base = 0; base < deg; base += 64){
        int e = base + lane;
        if (e < deg) ew2[off + e] *= inv;
    }
}

// ---------------- layer-2 aggregation -> out [N][16] fp32 ----------------
__global__ __launch_bounds__(256) void agg2(const float* __restrict__ h2,
        const float* __restrict__ ew2, const float* __restrict__ wself2,
        const int* __restrict__ offsets, const int* __restrict__ esrc,
        const float* __restrict__ b2, float* __restrict__ out){
    int d = blockIdx.x * 4 + (threadIdx.x >> 6);
    int lane = threadIdx.x & 63;
    if (d >= N_NODES) return;
    int off = offsets[d], deg = offsets[d + 1] - off;
    int sg = lane >> 4, col = lane & 15;
    float acc = (sg == 0) ? wself2[d] * h2[(size_t)d * NCLS + col] : 0.f;
    for (int base = 0; base < deg; base += 4){
        int i = base + sg;
        if (i < deg){
            int s = esrc[off + i];
            acc += ew2[off + i] * h2[(size_t)s * NCLS + col];
        }
    }
    acc += __shfl_xor(acc, 16);
    acc += __shfl_xor(acc, 32);
    if (lane < NCLS) out[(size_t)d * NCLS + lane] = acc + b2[lane];
}

extern "C" void kernel_launch(void* const* d_in, const int* in_sizes, int n_in,
                              void* d_out, int out_size, void* d_ws, size_t ws_size,
                              hipStream_t stream){
    const float* x   = (const float*)d_in[0];
    const int*   ei  = (const int*)d_in[1];
    const int*   src = ei;
    const int*   dst = ei + NEDGE;
    const float* W1  = (const float*)d_in[2];
    const float* as1 = (const float*)d_in[3];
    const float* ad1 = (const float*)d_in[4];
    const float* b1  = (const float*)d_in[5];
    const float* W2  = (const float*)d_in[6];
    const float* as2 = (const float*)d_in[7];
    const float* ad2 = (const float*)d_in[8];
    const float* b2  = (const float*)d_in[9];
    float* out = (float*)d_out;

    char* p = (char*)d_ws;
    auto carve = [&](size_t bytes) -> char* {
        char* r = p; p += (bytes + 255) & ~(size_t)255; return r;
    };
    unsigned short* xb   = (unsigned short*)carve((size_t)N_NODES * F_INK * 2);
    unsigned short* w1t  = (unsigned short*)carve((size_t)HH * F_INK * 2);
    unsigned short* w2t  = (unsigned short*)carve((size_t)HH * NCLS * 2);
    unsigned short* h1b  = (unsigned short*)carve((size_t)N_NODES * HH * 2);
    float* al1s  = (float*)carve((size_t)N_NODES * HEADS * 4);
    float* al1d  = (float*)carve((size_t)N_NODES * HEADS * 4);
    int* counts  = (int*)carve((size_t)N_NODES * 4);
    int* cursor  = (int*)carve((size_t)N_NODES * 4);
    int* offsets = (int*)carve((size_t)(N_NODES + 1) * 4);
    int* esrc    = (int*)carve((size_t)NEDGE * 4);
    float* ew    = (float*)carve((size_t)NEDGE * HEADS * 4);
    float* wself = (float*)carve((size_t)N_NODES * HEADS * 4);
    unsigned short* x2b = (unsigned short*)carve((size_t)N_NODES * HH * 2);
    float* h2    = (float*)carve((size_t)N_NODES * NCLS * 4);
    float* al2s  = (float*)carve((size_t)N_NODES * 4);
    float* al2d  = (float*)carve((size_t)N_NODES * 4);
    float* ew2   = (float*)carve((size_t)NEDGE * 4);
    float* wself2= (float*)carve((size_t)N_NODES * 4);
    if ((size_t)(p - (char*)d_ws) > ws_size) return;  // workspace too small

    hipMemsetAsync(counts, 0, N_NODES * 4, stream);
    hipMemsetAsync(cursor, 0, N_NODES * 4, stream);

    cvt_f32_bf16<<<2048, 256, 0, stream>>>(x, xb, N_NODES * F_INK / 4);
    cvt_w1t<<<(F_INK * HH + 255) / 256, 256, 0, stream>>>(W1, w1t);
    cvt_w2t<<<(HH * NCLS + 255) / 256, 256, 0, stream>>>(W2, w2t);
    count_edges<<<(NEDGE + 255) / 256, 256, 0, stream>>>(dst, counts);
    scan_offsets<<<1, 1024, 0, stream>>>(counts, offsets);
    scatter_edges<<<(NEDGE + 255) / 256, 256, 0, stream>>>(src, dst, offsets, cursor, esrc);
    gemm1<<<8 * 128, 256, 0, stream>>>(xb, w1t, h1b);
    attn1_dots<<<(N_NODES + 3) / 4, 256, 0, stream>>>(h1b, as1, ad1, al1s, al1d);
    softmax1<<<(N_NODES + 3) / 4, 256, 0, stream>>>(al1s, al1d, offsets, esrc, ew, wself);
    agg1<<<N_NODES, 256, 0, stream>>>(h1b, ew, wself, offsets, esrc, b1, x2b);
    gemm2<<<(N_NODES / 16 + 3) / 4, 256, 0, stream>>>(x2b, w2t, as2, ad2, h2, al2s, al2d);
    softmax2<<<(N_NODES + 3) / 4, 256, 0, stream>>>(al2s, al2d, offsets, esrc, ew2, wself2);
    agg2<<<(N_NODES + 3) / 4, 256, 0, stream>>>(h2, ew2, wself2, offsets, esrc, b2, out);
}

// Round 7
// 280.574 us; speedup vs baseline: 2.4936x; 1.2380x over previous
//
#include <hip/hip_runtime.h>
#include <hip/hip_bf16.h>
#include <math.h>

#define N_NODES 50000
#define F_INK   256
#define HEADS   8
#define HID     64
#define HH      512     // HEADS*HID
#define NCLS    16
#define NEDGE   400000
#define NEG_SLOPE 0.2f

#define BCOLS 64
#define KPAD  264       // 256 + 8 bf16 pad -> optimal quad-bank spread
#define NBLK_SCAN ((N_NODES + 255) / 256)   // 196

typedef __attribute__((ext_vector_type(8))) short short8;
typedef __attribute__((ext_vector_type(4))) short sh4;
typedef __attribute__((ext_vector_type(4))) float float4v;

__device__ __forceinline__ float bf2f(unsigned short u){
    unsigned int x = ((unsigned int)u) << 16;
    float f; __builtin_memcpy(&f, &x, 4); return f;
}
__device__ __forceinline__ unsigned short f2bf(float f){
    unsigned int x; __builtin_memcpy(&x, &f, 4);
    unsigned int r = x + 0x7FFFu + ((x >> 16) & 1u);   // RNE
    return (unsigned short)(r >> 16);
}
__device__ __forceinline__ float lrelu(float a){ return a > 0.f ? a : NEG_SLOPE * a; }

// ---------------- conversions ----------------
__global__ void cvt_f32_bf16(const float* __restrict__ in, unsigned short* __restrict__ out, int n4){
    int i = blockIdx.x * blockDim.x + threadIdx.x;
    int stride = gridDim.x * blockDim.x;
    for (; i < n4; i += stride){
        float4v f = *(const float4v*)(in + (size_t)i * 4);
        sh4 o;
#pragma unroll
        for (int j = 0; j < 4; j++) o[j] = (short)f2bf(f[j]);
        *(sh4*)(out + (size_t)i * 4) = o;
    }
}

// W1 [256][512] fp32 -> W1T [512][256] bf16
__global__ void cvt_w1t(const float* __restrict__ W1, unsigned short* __restrict__ W1T){
    int i = blockIdx.x * blockDim.x + threadIdx.x;
    if (i >= F_INK * HH) return;
    int k = i / HH, c = i % HH;
    W1T[c * F_INK + k] = f2bf(W1[i]);
}

// W2 [512][16] fp32 -> W2T [16][512] bf16
__global__ void cvt_w2t(const float* __restrict__ W2, unsigned short* __restrict__ W2T){
    int i = blockIdx.x * blockDim.x + threadIdx.x;
    if (i >= HH * NCLS) return;
    int k = i / NCLS, c = i % NCLS;
    W2T[c * HH + k] = f2bf(W2[i]);
}

// ---------------- CSR build ----------------
__global__ void count_edges(const int* __restrict__ dst, int* __restrict__ counts){
    int e = blockIdx.x * blockDim.x + threadIdx.x;
    if (e < NEDGE) atomicAdd(&counts[dst[e]], 1);
}

// phase 1: per-block (256-node chunk) sums
__global__ __launch_bounds__(256) void scan_part(const int* __restrict__ counts,
                                                 int* __restrict__ blocksums){
    __shared__ int red[256];
    int i = blockIdx.x * 256 + threadIdx.x;
    int v = (i < N_NODES) ? counts[i] : 0;
    red[threadIdx.x] = v; __syncthreads();
    for (int off = 128; off > 0; off >>= 1){
        if (threadIdx.x < off) red[threadIdx.x] += red[threadIdx.x + off];
        __syncthreads();
    }
    if (threadIdx.x == 0) blocksums[blockIdx.x] = red[0];
}

// phase 2: scan the 196 block sums (single small block)
__global__ __launch_bounds__(256) void scan_top(const int* __restrict__ blocksums,
                                                int* __restrict__ blockbase,
                                                int* __restrict__ offsets){
    __shared__ int s[256];
    int t = threadIdx.x;
    int v = (t < NBLK_SCAN) ? blocksums[t] : 0;
    s[t] = v; __syncthreads();
    int val = v;
    for (int off = 1; off < 256; off <<= 1){
        int o2 = (t >= off) ? s[t - off] : 0;
        __syncthreads();
        val += o2; s[t] = val;
        __syncthreads();
    }
    if (t < NBLK_SCAN) blockbase[t] = val - v;   // exclusive
    if (t == 255) offsets[N_NODES] = s[255];     // grand total
}

// phase 3: in-block exclusive scan + base
__global__ __launch_bounds__(256) void scan_write(const int* __restrict__ counts,
                                                  const int* __restrict__ blockbase,
                                                  int* __restrict__ offsets){
    __shared__ int s[256];
    int i = blockIdx.x * 256 + threadIdx.x;
    int t = threadIdx.x;
    int v = (i < N_NODES) ? counts[i] : 0;
    s[t] = v; __syncthreads();
    int val = v;
    for (int off = 1; off < 256; off <<= 1){
        int o2 = (t >= off) ? s[t - off] : 0;
        __syncthreads();
        val += o2; s[t] = val;
        __syncthreads();
    }
    if (i < N_NODES) offsets[i] = blockbase[blockIdx.x] + val - v;
}

__global__ void scatter_edges(const int* __restrict__ src, const int* __restrict__ dst,
                              const int* __restrict__ offsets, int* __restrict__ cursor,
                              int* __restrict__ esrc){
    int e = blockIdx.x * blockDim.x + threadIdx.x;
    if (e < NEDGE){
        int d = dst[e];
        int pos = offsets[d] + atomicAdd(&cursor[d], 1);
        esrc[pos] = src[e];
    }
}

// ---------------- GEMM1: h1 = bf16(x) @ bf16(W1), output bf16 [N][512] ----------------
__global__ __launch_bounds__(256) void gemm1(const unsigned short* __restrict__ xb,
                                             const unsigned short* __restrict__ w1t,
                                             unsigned short* __restrict__ h1b){
    __shared__ unsigned short bs[BCOLS * KPAD];   // 33 KB
    int cb  = blockIdx.x & 7;          // col panel: cols [cb*64, cb*64+64)
    int rg  = blockIdx.x >> 3;
    int nrg = gridDim.x >> 3;
    {   // stage B panel once
        int kc = threadIdx.x & 31;     // k-chunk of 8
        int c0 = threadIdx.x >> 5;     // 0..7
#pragma unroll
        for (int it = 0; it < 8; it++){
            int col = it * 8 + c0;
            short8 v = *(const short8*)(w1t + (size_t)(cb * BCOLS + col) * F_INK + kc * 8);
            *(short8*)(&bs[col * KPAD + kc * 8]) = v;
        }
    }
    __syncthreads();
    int w    = threadIdx.x >> 6;
    int lane = threadIdx.x & 63;
    int lr = lane & 15, lk = lane >> 4;
    const int nchunk = (N_NODES + 63) / 64;       // 782
    for (int ch = rg; ch < nchunk; ch += nrg){
        int rowbase = ch * 64 + w * 16;
        if (rowbase >= N_NODES) continue;
        short8 a[8];
#pragma unroll
        for (int ks = 0; ks < 8; ks++)
            a[ks] = *(const short8*)(xb + (size_t)(rowbase + lr) * F_INK + ks * 32 + lk * 8);
#pragma unroll
        for (int ct = 0; ct < 4; ct++){
            float4v acc = {0.f, 0.f, 0.f, 0.f};
#pragma unroll
            for (int ks = 0; ks < 8; ks++){
                short8 b = *(const short8*)(&bs[(ct * 16 + lr) * KPAD + ks * 32 + lk * 8]);
                acc = __builtin_amdgcn_mfma_f32_16x16x32_bf16(a[ks], b, acc, 0, 0, 0);
            }
#pragma unroll
            for (int r = 0; r < 4; r++)
                h1b[(size_t)(rowbase + lk * 4 + r) * HH + cb * BCOLS + ct * 16 + lr] = f2bf(acc[r]);
        }
    }
}

// ---------------- attention dots: al_src/al_dst [N][8] ----------------
__global__ __launch_bounds__(256) void attn1_dots(const unsigned short* __restrict__ h1b,
        const float* __restrict__ a_src, const float* __restrict__ a_dst,
        float* __restrict__ al_s, float* __restrict__ al_d){
    int n = blockIdx.x * 4 + (threadIdx.x >> 6);
    int lane = threadIdx.x & 63;
    if (n >= N_NODES) return;
    short8 v = *(const short8*)(h1b + (size_t)n * HH + lane * 8);
    int head = lane >> 3;
    int j0 = (lane & 7) * 8;
    float ps = 0.f, pd = 0.f;
#pragma unroll
    for (int j = 0; j < 8; j++){
        float hv = bf2f((unsigned short)v[j]);
        ps += hv * a_src[head * HID + j0 + j];
        pd += hv * a_dst[head * HID + j0 + j];
    }
#pragma unroll
    for (int off = 1; off < 8; off <<= 1){
        ps += __shfl_xor(ps, off);
        pd += __shfl_xor(pd, off);
    }
    if ((lane & 7) == 0){
        al_s[n * HEADS + head] = ps;
        al_d[n * HEADS + head] = pd;
    }
}

// ---------------- layer-1 softmax weights: ew[p][8], wself[d][8] ----------------
__global__ __launch_bounds__(256) void softmax1(
        const float* __restrict__ al_s, const float* __restrict__ al_d,
        const int* __restrict__ offsets, const int* __restrict__ esrc,
        float* __restrict__ ew, float* __restrict__ wself){
    int d = blockIdx.x * 4 + (threadIdx.x >> 6);
    int lane = threadIdx.x & 63;
    if (d >= N_NODES) return;
    int h = lane & 7, i = lane >> 3;
    int off = offsets[d], deg = offsets[d + 1] - off;
    float ald = al_d[d * HEADS + h];
    float aself = lrelu(al_s[d * HEADS + h] + ald);
    float m = aself;
    for (int base = 0; base < deg; base += 8){
        int e = base + i;
        float a = -1e30f;
        if (e < deg) a = lrelu(al_s[esrc[off + e] * HEADS + h] + ald);
        a = fmaxf(a, __shfl_xor(a, 8));
        a = fmaxf(a, __shfl_xor(a, 16));
        a = fmaxf(a, __shfl_xor(a, 32));
        m = fmaxf(m, a);
    }
    float denom = __expf(aself - m);
    for (int base = 0; base < deg; base += 8){
        int e = base + i;
        float w = 0.f;
        if (e < deg){
            w = __expf(lrelu(al_s[esrc[off + e] * HEADS + h] + ald) - m);
            ew[(size_t)(off + e) * HEADS + h] = w;
        }
        float ws = w;
        ws += __shfl_xor(ws, 8);
        ws += __shfl_xor(ws, 16);
        ws += __shfl_xor(ws, 32);
        denom += ws;
    }
    float inv = 1.f / denom;
    if (i == 0) wself[d * HEADS + h] = __expf(aself - m) * inv;
    for (int base = 0; base < deg; base += 8){
        int e = base + i;
        if (e < deg) ew[(size_t)(off + e) * HEADS + h] *= inv;
    }
}

// ---------------- layer-1 aggregation (wave-per-edge-subset) + elu -> x2b ----------------
__global__ __launch_bounds__(256) void agg1(const unsigned short* __restrict__ h1b,
        const float* __restrict__ ew, const float* __restrict__ wself,
        const int* __restrict__ offsets, const int* __restrict__ esrc,
        const float* __restrict__ b1, unsigned short* __restrict__ x2b){
    __shared__ float s_red[4][HH];    // 8 KB
    int d = blockIdx.x;
    int w = threadIdx.x >> 6;
    int lane = threadIdx.x & 63;
    int g = lane >> 3;                 // head
    int c0 = (lane & 7) * 8;           // col base within head
    int off = offsets[d], deg = offsets[d + 1] - off;
    float acc[8];
#pragma unroll
    for (int j = 0; j < 8; j++) acc[j] = 0.f;
    if (w == 0){                       // self edge
        float w0 = wself[d * HEADS + g];
        short8 v = *(const short8*)(h1b + (size_t)d * HH + g * HID + c0);
#pragma unroll
        for (int j = 0; j < 8; j++) acc[j] += w0 * bf2f((unsigned short)v[j]);
    }
    int e = w;
    for (; e + 4 < deg; e += 8){       // two edges in flight
        int s0 = esrc[off + e], s1 = esrc[off + e + 4];
        float w0 = ew[(size_t)(off + e) * HEADS + g];
        float w1 = ew[(size_t)(off + e + 4) * HEADS + g];
        short8 v0 = *(const short8*)(h1b + (size_t)s0 * HH + g * HID + c0);
        short8 v1 = *(const short8*)(h1b + (size_t)s1 * HH + g * HID + c0);
#pragma unroll
        for (int j = 0; j < 8; j++) acc[j] += w0 * bf2f((unsigned short)v0[j]);
#pragma unroll
        for (int j = 0; j < 8; j++) acc[j] += w1 * bf2f((unsigned short)v1[j]);
    }
    if (e < deg){
        int s0 = esrc[off + e];
        float w0 = ew[(size_t)(off + e) * HEADS + g];
        short8 v0 = *(const short8*)(h1b + (size_t)s0 * HH + g * HID + c0);
#pragma unroll
        for (int j = 0; j < 8; j++) acc[j] += w0 * bf2f((unsigned short)v0[j]);
    }
#pragma unroll
    for (int j = 0; j < 8; j++) s_red[w][g * HID + c0 + j] = acc[j];
    __syncthreads();
    int col = threadIdx.x * 2;
    float v0 = s_red[0][col] + s_red[1][col] + s_red[2][col] + s_red[3][col] + b1[col];
    float v1 = s_red[0][col+1] + s_red[1][col+1] + s_red[2][col+1] + s_red[3][col+1] + b1[col+1];
    v0 = v0 > 0.f ? v0 : __expf(v0) - 1.f;   // elu
    v1 = v1 > 0.f ? v1 : __expf(v1) - 1.f;
    unsigned int o = ((unsigned int)f2bf(v1) << 16) | f2bf(v0);
    *(unsigned int*)(x2b + (size_t)d * HH + col) = o;
}

// ---------------- layer-2 GEMM via MFMA: h2 = x2b @ W2 (+ fused attention dots) --------
__global__ __launch_bounds__(256) void gemm2(const unsigned short* __restrict__ x2b,
        const unsigned short* __restrict__ w2t,
        const float* __restrict__ a_s2, const float* __restrict__ a_d2,
        float* __restrict__ h2, float* __restrict__ al2s, float* __restrict__ al2d){
    int wave = (blockIdx.x * blockDim.x + threadIdx.x) >> 6;
    int lane = threadIdx.x & 63;
    if (wave >= N_NODES / 16) return;
    int rowbase = wave * 16;
    int lr = lane & 15, lk = lane >> 4;
    float4v acc = {0.f, 0.f, 0.f, 0.f};
#pragma unroll
    for (int ks = 0; ks < 16; ks++){
        short8 a = *(const short8*)(x2b + (size_t)(rowbase + lr) * HH + ks * 32 + lk * 8);
        short8 b = *(const short8*)(w2t + (size_t)lr * HH + ks * 32 + lk * 8);
        acc = __builtin_amdgcn_mfma_f32_16x16x32_bf16(a, b, acc, 0, 0, 0);
    }
#pragma unroll
    for (int r = 0; r < 4; r++)
        h2[(size_t)(rowbase + lk * 4 + r) * NCLS + lr] = acc[r];
    float s_a = a_s2[lr], d_a = a_d2[lr];
#pragma unroll
    for (int r = 0; r < 4; r++){
        float ps = acc[r] * s_a, pd = acc[r] * d_a;
#pragma unroll
        for (int off = 1; off < 16; off <<= 1){
            ps += __shfl_xor(ps, off);
            pd += __shfl_xor(pd, off);
        }
        if (lr == 0){
            al2s[rowbase + lk * 4 + r] = ps;
            al2d[rowbase + lk * 4 + r] = pd;
        }
    }
}

// ---------------- layer-2 softmax weights ----------------
__global__ __launch_bounds__(256) void softmax2(
        const float* __restrict__ al2s, const float* __restrict__ al2d,
        const int* __restrict__ offsets, const int* __restrict__ esrc,
        float* __restrict__ ew2, float* __restrict__ wself2){
    int d = blockIdx.x * 4 + (threadIdx.x >> 6);
    int lane = threadIdx.x & 63;
    if (d >= N_NODES) return;
    int off = offsets[d], deg = offsets[d + 1] - off;
    float ald = al2d[d];
    float aself = lrelu(al2s[d] + ald);
    float m = aself;
    for (int base = 0; base < deg; base += 64){
        int e = base + lane;
        float a = (e < deg) ? lrelu(al2s[esrc[off + e]] + ald) : -1e30f;
#pragma unroll
        for (int o = 1; o < 64; o <<= 1) a = fmaxf(a, __shfl_xor(a, o));
        m = fmaxf(m, a);
    }
    float denom = __expf(aself - m);
    for (int base = 0; base < deg; base += 64){
        int e = base + lane;
        float w = 0.f;
        if (e < deg){
            w = __expf(lrelu(al2s[esrc[off + e]] + ald) - m);
            ew2[off + e] = w;
        }
#pragma unroll
        for (int o = 1; o < 64; o <<= 1) w += __shfl_xor(w, o);
        denom += w;
    }
    float inv = 1.f / denom;
    if (lane == 0) wself2[d] = __expf(aself - m) * inv;
    for (int base = 0; base < deg; base += 64){
        int e = base + lane;
        if (e < deg) ew2[off + e] *= inv;
    }
}

// ---------------- layer-2 aggregation -> out [N][16] fp32 ----------------
__global__ __launch_bounds__(256) void agg2(const float* __restrict__ h2,
        const float* __restrict__ ew2, const float* __restrict__ wself2,
        const int* __restrict__ offsets, const int* __restrict__ esrc,
        const float* __restrict__ b2, float* __restrict__ out){
    int d = blockIdx.x * 4 + (threadIdx.x >> 6);
    int lane = threadIdx.x & 63;
    if (d >= N_NODES) return;
    int off = offsets[d], deg = offsets[d + 1] - off;
    int sg = lane >> 4, col = lane & 15;
    float acc = (sg == 0) ? wself2[d] * h2[(size_t)d * NCLS + col] : 0.f;
    for (int base = 0; base < deg; base += 4){
        int i = base + sg;
        if (i < deg){
            int s = esrc[off + i];
            acc += ew2[off + i] * h2[(size_t)s * NCLS + col];
        }
    }
    acc += __shfl_xor(acc, 16);
    acc += __shfl_xor(acc, 32);
    if (lane < NCLS) out[(size_t)d * NCLS + lane] = acc + b2[lane];
}

extern "C" void kernel_launch(void* const* d_in, const int* in_sizes, int n_in,
                              void* d_out, int out_size, void* d_ws, size_t ws_size,
                              hipStream_t stream){
    const float* x   = (const float*)d_in[0];
    const int*   ei  = (const int*)d_in[1];
    const int*   src = ei;
    const int*   dst = ei + NEDGE;
    const float* W1  = (const float*)d_in[2];
    const float* as1 = (const float*)d_in[3];
    const float* ad1 = (const float*)d_in[4];
    const float* b1  = (const float*)d_in[5];
    const float* W2  = (const float*)d_in[6];
    const float* as2 = (const float*)d_in[7];
    const float* ad2 = (const float*)d_in[8];
    const float* b2  = (const float*)d_in[9];
    float* out = (float*)d_out;

    char* p = (char*)d_ws;
    auto carve = [&](size_t bytes) -> char* {
        char* r = p; p += (bytes + 255) & ~(size_t)255; return r;
    };
    unsigned short* xb   = (unsigned short*)carve((size_t)N_NODES * F_INK * 2);
    unsigned short* w1t  = (unsigned short*)carve((size_t)HH * F_INK * 2);
    unsigned short* w2t  = (unsigned short*)carve((size_t)HH * NCLS * 2);
    unsigned short* h1b  = (unsigned short*)carve((size_t)N_NODES * HH * 2);
    float* al1s  = (float*)carve((size_t)N_NODES * HEADS * 4);
    float* al1d  = (float*)carve((size_t)N_NODES * HEADS * 4);
    int* counts  = (int*)carve((size_t)N_NODES * 4);
    int* cursor  = (int*)carve((size_t)N_NODES * 4);
    int* offsets = (int*)carve((size_t)(N_NODES + 1) * 4);
    int* blocksums = (int*)carve((size_t)NBLK_SCAN * 4);
    int* blockbase = (int*)carve((size_t)NBLK_SCAN * 4);
    int* esrc    = (int*)carve((size_t)NEDGE * 4);
    float* ew    = (float*)carve((size_t)NEDGE * HEADS * 4);
    float* wself = (float*)carve((size_t)N_NODES * HEADS * 4);
    unsigned short* x2b = (unsigned short*)carve((size_t)N_NODES * HH * 2);
    float* h2    = (float*)carve((size_t)N_NODES * NCLS * 4);
    float* al2s  = (float*)carve((size_t)N_NODES * 4);
    float* al2d  = (float*)carve((size_t)N_NODES * 4);
    float* ew2   = (float*)carve((size_t)NEDGE * 4);
    float* wself2= (float*)carve((size_t)N_NODES * 4);
    if ((size_t)(p - (char*)d_ws) > ws_size) return;  // workspace too small

    hipMemsetAsync(counts, 0, N_NODES * 4, stream);
    hipMemsetAsync(cursor, 0, N_NODES * 4, stream);

    cvt_f32_bf16<<<2048, 256, 0, stream>>>(x, xb, N_NODES * F_INK / 4);
    cvt_w1t<<<(F_INK * HH + 255) / 256, 256, 0, stream>>>(W1, w1t);
    cvt_w2t<<<(HH * NCLS + 255) / 256, 256, 0, stream>>>(W2, w2t);
    count_edges<<<(NEDGE + 255) / 256, 256, 0, stream>>>(dst, counts);
    scan_part<<<NBLK_SCAN, 256, 0, stream>>>(counts, blocksums);
    scan_top<<<1, 256, 0, stream>>>(blocksums, blockbase, offsets);
    scan_write<<<NBLK_SCAN, 256, 0, stream>>>(counts, blockbase, offsets);
    scatter_edges<<<(NEDGE + 255) / 256, 256, 0, stream>>>(src, dst, offsets, cursor, esrc);
    gemm1<<<8 * 128, 256, 0, stream>>>(xb, w1t, h1b);
    attn1_dots<<<(N_NODES + 3) / 4, 256, 0, stream>>>(h1b, as1, ad1, al1s, al1d);
    softmax1<<<(N_NODES + 3) / 4, 256, 0, stream>>>(al1s, al1d, offsets, esrc, ew, wself);
    agg1<<<N_NODES, 256, 0, stream>>>(h1b, ew, wself, offsets, esrc, b1, x2b);
    gemm2<<<(N_NODES / 16 + 3) / 4, 256, 0, stream>>>(x2b, w2t, as2, ad2, h2, al2s, al2d);
    softmax2<<<(N_NODES + 3) / 4, 256, 0, stream>>>(al2s, al2d, offsets, esrc, ew2, wself2);
    agg2<<<(N_NODES + 3) / 4, 256, 0, stream>>>(h2, ew2, wself2, offsets, esrc, b2, out);
}

// Round 8
// 271.876 us; speedup vs baseline: 2.5734x; 1.0320x over previous
//
#include <hip/hip_runtime.h>
#include <hip/hip_bf16.h>
#include <math.h>

#define N_NODES 50000
#define F_INK   256
#define HEADS   8
#define HID     64
#define HH      512     // HEADS*HID
#define NCLS    16
#define NEDGE   400000
#define NEG_SLOPE 0.2f

#define BCOLS 64
#define KPAD  264       // 256 + 8 bf16 pad -> optimal quad-bank spread
#define NBLK_SCAN ((N_NODES + 255) / 256)   // 196

typedef __attribute__((ext_vector_type(8))) short short8;
typedef __attribute__((ext_vector_type(4))) short sh4;
typedef __attribute__((ext_vector_type(4))) float float4v;

__device__ __forceinline__ float bf2f(unsigned short u){
    unsigned int x = ((unsigned int)u) << 16;
    float f; __builtin_memcpy(&f, &x, 4); return f;
}
__device__ __forceinline__ unsigned short f2bf(float f){
    unsigned int x; __builtin_memcpy(&x, &f, 4);
    unsigned int r = x + 0x7FFFu + ((x >> 16) & 1u);   // RNE
    return (unsigned short)(r >> 16);
}
__device__ __forceinline__ float lrelu(float a){ return a > 0.f ? a : NEG_SLOPE * a; }

// dword-level bf16x2 unpack + fma: 1 VALU unpack + 1 fma per element
__device__ __forceinline__ void fma8(float* acc, float w, short8 v){
    unsigned int u[4]; __builtin_memcpy(u, &v, 16);
#pragma unroll
    for (int j = 0; j < 4; j++){
        acc[2*j]   += w * __uint_as_float(u[j] << 16);
        acc[2*j+1] += w * __uint_as_float(u[j] & 0xffff0000u);
    }
}

// ---------------- conversions ----------------
__global__ void cvt_f32_bf16(const float* __restrict__ in, unsigned short* __restrict__ out, int n4){
    int i = blockIdx.x * blockDim.x + threadIdx.x;
    int stride = gridDim.x * blockDim.x;
    for (; i < n4; i += stride){
        float4v f = *(const float4v*)(in + (size_t)i * 4);
        sh4 o;
#pragma unroll
        for (int j = 0; j < 4; j++) o[j] = (short)f2bf(f[j]);
        *(sh4*)(out + (size_t)i * 4) = o;
    }
}

// W1 [256][512] fp32 -> W1T [512][256] bf16
__global__ void cvt_w1t(const float* __restrict__ W1, unsigned short* __restrict__ W1T){
    int i = blockIdx.x * blockDim.x + threadIdx.x;
    if (i >= F_INK * HH) return;
    int k = i / HH, c = i % HH;
    W1T[c * F_INK + k] = f2bf(W1[i]);
}

// W2 [512][16] fp32 -> W2T [16][512] bf16
__global__ void cvt_w2t(const float* __restrict__ W2, unsigned short* __restrict__ W2T){
    int i = blockIdx.x * blockDim.x + threadIdx.x;
    if (i >= HH * NCLS) return;
    int k = i / NCLS, c = i % NCLS;
    W2T[c * HH + k] = f2bf(W2[i]);
}

// ---------------- CSR build ----------------
__global__ void count_edges(const int* __restrict__ dst, int* __restrict__ counts){
    int e = blockIdx.x * blockDim.x + threadIdx.x;
    if (e < NEDGE) atomicAdd(&counts[dst[e]], 1);
}

__global__ __launch_bounds__(256) void scan_part(const int* __restrict__ counts,
                                                 int* __restrict__ blocksums){
    __shared__ int red[256];
    int i = blockIdx.x * 256 + threadIdx.x;
    int v = (i < N_NODES) ? counts[i] : 0;
    red[threadIdx.x] = v; __syncthreads();
    for (int off = 128; off > 0; off >>= 1){
        if (threadIdx.x < off) red[threadIdx.x] += red[threadIdx.x + off];
        __syncthreads();
    }
    if (threadIdx.x == 0) blocksums[blockIdx.x] = red[0];
}

__global__ __launch_bounds__(256) void scan_top(const int* __restrict__ blocksums,
                                                int* __restrict__ blockbase,
                                                int* __restrict__ offsets){
    __shared__ int s[256];
    int t = threadIdx.x;
    int v = (t < NBLK_SCAN) ? blocksums[t] : 0;
    s[t] = v; __syncthreads();
    int val = v;
    for (int off = 1; off < 256; off <<= 1){
        int o2 = (t >= off) ? s[t - off] : 0;
        __syncthreads();
        val += o2; s[t] = val;
        __syncthreads();
    }
    if (t < NBLK_SCAN) blockbase[t] = val - v;   // exclusive
    if (t == 255) offsets[N_NODES] = s[255];     // grand total
}

__global__ __launch_bounds__(256) void scan_write(const int* __restrict__ counts,
                                                  const int* __restrict__ blockbase,
                                                  int* __restrict__ offsets){
    __shared__ int s[256];
    int i = blockIdx.x * 256 + threadIdx.x;
    int t = threadIdx.x;
    int v = (i < N_NODES) ? counts[i] : 0;
    s[t] = v; __syncthreads();
    int val = v;
    for (int off = 1; off < 256; off <<= 1){
        int o2 = (t >= off) ? s[t - off] : 0;
        __syncthreads();
        val += o2; s[t] = val;
        __syncthreads();
    }
    if (i < N_NODES) offsets[i] = blockbase[blockIdx.x] + val - v;
}

__global__ void scatter_edges(const int* __restrict__ src, const int* __restrict__ dst,
                              const int* __restrict__ offsets, int* __restrict__ cursor,
                              int* __restrict__ esrc){
    int e = blockIdx.x * blockDim.x + threadIdx.x;
    if (e < NEDGE){
        int d = dst[e];
        int pos = offsets[d] + atomicAdd(&cursor[d], 1);
        esrc[pos] = src[e];
    }
}

// ---------------- GEMM1: h1 = bf16(x) @ bf16(W1), output bf16 [N][512] ----------------
__global__ __launch_bounds__(256) void gemm1(const unsigned short* __restrict__ xb,
                                             const unsigned short* __restrict__ w1t,
                                             unsigned short* __restrict__ h1b){
    __shared__ unsigned short bs[BCOLS * KPAD];   // 33 KB
    int cb  = blockIdx.x & 7;          // col panel: cols [cb*64, cb*64+64)
    int rg  = blockIdx.x >> 3;
    int nrg = gridDim.x >> 3;
    {   // stage B panel once
        int kc = threadIdx.x & 31;
        int c0 = threadIdx.x >> 5;
#pragma unroll
        for (int it = 0; it < 8; it++){
            int col = it * 8 + c0;
            short8 v = *(const short8*)(w1t + (size_t)(cb * BCOLS + col) * F_INK + kc * 8);
            *(short8*)(&bs[col * KPAD + kc * 8]) = v;
        }
    }
    __syncthreads();
    int w    = threadIdx.x >> 6;
    int lane = threadIdx.x & 63;
    int lr = lane & 15, lk = lane >> 4;
    const int nchunk = (N_NODES + 63) / 64;       // 782
    for (int ch = rg; ch < nchunk; ch += nrg){
        int rowbase = ch * 64 + w * 16;
        if (rowbase >= N_NODES) continue;
        short8 a[8];
#pragma unroll
        for (int ks = 0; ks < 8; ks++)
            a[ks] = *(const short8*)(xb + (size_t)(rowbase + lr) * F_INK + ks * 32 + lk * 8);
#pragma unroll
        for (int ct = 0; ct < 4; ct++){
            float4v acc = {0.f, 0.f, 0.f, 0.f};
#pragma unroll
            for (int ks = 0; ks < 8; ks++){
                short8 b = *(const short8*)(&bs[(ct * 16 + lr) * KPAD + ks * 32 + lk * 8]);
                acc = __builtin_amdgcn_mfma_f32_16x16x32_bf16(a[ks], b, acc, 0, 0, 0);
            }
#pragma unroll
            for (int r = 0; r < 4; r++)
                h1b[(size_t)(rowbase + lk * 4 + r) * HH + cb * BCOLS + ct * 16 + lr] = f2bf(acc[r]);
        }
    }
}

// ---------------- attention dots: al_src/al_dst [N][8] ----------------
__global__ __launch_bounds__(256) void attn1_dots(const unsigned short* __restrict__ h1b,
        const float* __restrict__ a_src, const float* __restrict__ a_dst,
        float* __restrict__ al_s, float* __restrict__ al_d){
    int n = blockIdx.x * 4 + (threadIdx.x >> 6);
    int lane = threadIdx.x & 63;
    if (n >= N_NODES) return;
    short8 v = *(const short8*)(h1b + (size_t)n * HH + lane * 8);
    int head = lane >> 3;
    int j0 = (lane & 7) * 8;
    float ps = 0.f, pd = 0.f;
#pragma unroll
    for (int j = 0; j < 8; j++){
        float hv = bf2f((unsigned short)v[j]);
        ps += hv * a_src[head * HID + j0 + j];
        pd += hv * a_dst[head * HID + j0 + j];
    }
#pragma unroll
    for (int off = 1; off < 8; off <<= 1){
        ps += __shfl_xor(ps, off);
        pd += __shfl_xor(pd, off);
    }
    if ((lane & 7) == 0){
        al_s[n * HEADS + head] = ps;
        al_d[n * HEADS + head] = pd;
    }
}

// ---------------- layer-1 softmax: raw weights ew, wselfr, dinv ----------------
__global__ __launch_bounds__(256) void softmax1(
        const float* __restrict__ al_s, const float* __restrict__ al_d,
        const int* __restrict__ offsets, const int* __restrict__ esrc,
        float* __restrict__ ew, float* __restrict__ wselfr, float* __restrict__ dinv){
    int d = blockIdx.x * 4 + (threadIdx.x >> 6);
    int lane = threadIdx.x & 63;
    if (d >= N_NODES) return;
    int h = lane & 7, i = lane >> 3;
    int off = offsets[d], deg = offsets[d + 1] - off;
    float ald = al_d[d * HEADS + h];
    float aself = lrelu(al_s[d * HEADS + h] + ald);
    float m = aself;
    for (int base = 0; base < deg; base += 8){
        int e = base + i;
        float a = -1e30f;
        if (e < deg) a = lrelu(al_s[esrc[off + e] * HEADS + h] + ald);
        a = fmaxf(a, __shfl_xor(a, 8));
        a = fmaxf(a, __shfl_xor(a, 16));
        a = fmaxf(a, __shfl_xor(a, 32));
        m = fmaxf(m, a);
    }
    float denom = __expf(aself - m);
    for (int base = 0; base < deg; base += 8){
        int e = base + i;
        float w = 0.f;
        if (e < deg){
            w = __expf(lrelu(al_s[esrc[off + e] * HEADS + h] + ald) - m);
            ew[(size_t)(off + e) * HEADS + h] = w;    // unnormalized
        }
        float ws = w;
        ws += __shfl_xor(ws, 8);
        ws += __shfl_xor(ws, 16);
        ws += __shfl_xor(ws, 32);
        denom += ws;
    }
    if (i == 0){
        wselfr[d * HEADS + h] = __expf(aself - m);    // unnormalized self weight
        dinv[d * HEADS + h]   = 1.f / denom;
    }
}

// ---------------- layer-1 aggregation: one wave per dst, no LDS ----------------
// lane covers head g = lane>>3, cols (lane&7)*8..+8 (16B loads); 4-deep edge unroll;
// row base via readfirstlane -> SALU addressing; normalize once in epilogue.
__global__ __launch_bounds__(256) void agg1(const unsigned short* __restrict__ h1b,
        const float* __restrict__ ew, const float* __restrict__ wselfr,
        const float* __restrict__ dinv,
        const int* __restrict__ offsets, const int* __restrict__ esrc,
        const float* __restrict__ b1, unsigned short* __restrict__ x2b){
    int d = blockIdx.x * 4 + (threadIdx.x >> 6);
    if (d >= N_NODES) return;
    int lane = threadIdx.x & 63;
    int g = lane >> 3;
    int cb = g * HID + (lane & 7) * 8;     // lane's column offset (loop-invariant)
    int off = offsets[d], deg = offsets[d + 1] - off;
    float acc[8];
    {   // self edge
        float w0 = wselfr[d * HEADS + g];
        short8 v = *(const short8*)(h1b + (size_t)d * HH + cb);
        unsigned int u[4]; __builtin_memcpy(u, &v, 16);
#pragma unroll
        for (int j = 0; j < 4; j++){
            acc[2*j]   = w0 * __uint_as_float(u[j] << 16);
            acc[2*j+1] = w0 * __uint_as_float(u[j] & 0xffff0000u);
        }
    }
    int e = 0;
    for (; e + 4 <= deg; e += 4){
        int s0 = __builtin_amdgcn_readfirstlane(esrc[off + e]);
        int s1 = __builtin_amdgcn_readfirstlane(esrc[off + e + 1]);
        int s2 = __builtin_amdgcn_readfirstlane(esrc[off + e + 2]);
        int s3 = __builtin_amdgcn_readfirstlane(esrc[off + e + 3]);
        float w0 = ew[(size_t)(off + e)     * HEADS + g];
        float w1 = ew[(size_t)(off + e + 1) * HEADS + g];
        float w2 = ew[(size_t)(off + e + 2) * HEADS + g];
        float w3 = ew[(size_t)(off + e + 3) * HEADS + g];
        short8 v0 = *(const short8*)(h1b + (size_t)s0 * HH + cb);
        short8 v1 = *(const short8*)(h1b + (size_t)s1 * HH + cb);
        short8 v2 = *(const short8*)(h1b + (size_t)s2 * HH + cb);
        short8 v3 = *(const short8*)(h1b + (size_t)s3 * HH + cb);
        fma8(acc, w0, v0); fma8(acc, w1, v1);
        fma8(acc, w2, v2); fma8(acc, w3, v3);
    }
    for (; e < deg; e++){
        int s0 = __builtin_amdgcn_readfirstlane(esrc[off + e]);
        float w0 = ew[(size_t)(off + e) * HEADS + g];
        short8 v0 = *(const short8*)(h1b + (size_t)s0 * HH + cb);
        fma8(acc, w0, v0);
    }
    float di = dinv[d * HEADS + g];
    unsigned short o8[8];
#pragma unroll
    for (int j = 0; j < 8; j++){
        float v = acc[j] * di + b1[cb + j];
        v = v > 0.f ? v : __expf(v) - 1.f;   // elu
        o8[j] = f2bf(v);
    }
    short8 ov; __builtin_memcpy(&ov, o8, 16);
    *(short8*)(x2b + (size_t)d * HH + cb) = ov;
}

// ---------------- layer-2 GEMM via MFMA: h2 = x2b @ W2 (+ fused attention dots) --------
__global__ __launch_bounds__(256) void gemm2(const unsigned short* __restrict__ x2b,
        const unsigned short* __restrict__ w2t,
        const float* __restrict__ a_s2, const float* __restrict__ a_d2,
        float* __restrict__ h2, float* __restrict__ al2s, float* __restrict__ al2d){
    int wave = (blockIdx.x * blockDim.x + threadIdx.x) >> 6;
    int lane = threadIdx.x & 63;
    if (wave >= N_NODES / 16) return;
    int rowbase = wave * 16;
    int lr = lane & 15, lk = lane >> 4;
    float4v acc = {0.f, 0.f, 0.f, 0.f};
#pragma unroll
    for (int ks = 0; ks < 16; ks++){
        short8 a = *(const short8*)(x2b + (size_t)(rowbase + lr) * HH + ks * 32 + lk * 8);
        short8 b = *(const short8*)(w2t + (size_t)lr * HH + ks * 32 + lk * 8);
        acc = __builtin_amdgcn_mfma_f32_16x16x32_bf16(a, b, acc, 0, 0, 0);
    }
#pragma unroll
    for (int r = 0; r < 4; r++)
        h2[(size_t)(rowbase + lk * 4 + r) * NCLS + lr] = acc[r];
    float s_a = a_s2[lr], d_a = a_d2[lr];
#pragma unroll
    for (int r = 0; r < 4; r++){
        float ps = acc[r] * s_a, pd = acc[r] * d_a;
#pragma unroll
        for (int off = 1; off < 16; off <<= 1){
            ps += __shfl_xor(ps, off);
            pd += __shfl_xor(pd, off);
        }
        if (lr == 0){
            al2s[rowbase + lk * 4 + r] = ps;
            al2d[rowbase + lk * 4 + r] = pd;
        }
    }
}

// ---------------- layer-2 softmax weights ----------------
__global__ __launch_bounds__(256) void softmax2(
        const float* __restrict__ al2s, const float* __restrict__ al2d,
        const int* __restrict__ offsets, const int* __restrict__ esrc,
        float* __restrict__ ew2, float* __restrict__ wself2){
    int d = blockIdx.x * 4 + (threadIdx.x >> 6);
    int lane = threadIdx.x & 63;
    if (d >= N_NODES) return;
    int off = offsets[d], deg = offsets[d + 1] - off;
    float ald = al2d[d];
    float aself = lrelu(al2s[d] + ald);
    float m = aself;
    for (int base = 0; base < deg; base += 64){
        int e = base + lane;
        float a = (e < deg) ? lrelu(al2s[esrc[off + e]] + ald) : -1e30f;
#pragma unroll
        for (int o = 1; o < 64; o <<= 1) a = fmaxf(a, __shfl_xor(a, o));
        m = fmaxf(m, a);
    }
    float denom = __expf(aself - m);
    for (int base = 0; base < deg; base += 64){
        int e = base + lane;
        float w = 0.f;
        if (e < deg){
            w = __expf(lrelu(al2s[esrc[off + e]] + ald) - m);
            ew2[off + e] = w;
        }
#pragma unroll
        for (int o = 1; o < 64; o <<= 1) w += __shfl_xor(w, o);
        denom += w;
    }
    float inv = 1.f / denom;
    if (lane == 0) wself2[d] = __expf(aself - m) * inv;
    for (int base = 0; base < deg; base += 64){
        int e = base + lane;
        if (e < deg) ew2[off + e] *= inv;
    }
}

// ---------------- layer-2 aggregation -> out [N][16] fp32 ----------------
__global__ __launch_bounds__(256) void agg2(const float* __restrict__ h2,
        const float* __restrict__ ew2, const float* __restrict__ wself2,
        const int* __restrict__ offsets, const int* __restrict__ esrc,
        const float* __restrict__ b2, float* __restrict__ out){
    int d = blockIdx.x * 4 + (threadIdx.x >> 6);
    int lane = threadIdx.x & 63;
    if (d >= N_NODES) return;
    int off = offsets[d], deg = offsets[d + 1] - off;
    int sg = lane >> 4, col = lane & 15;
    float acc = (sg == 0) ? wself2[d] * h2[(size_t)d * NCLS + col] : 0.f;
    for (int base = 0; base < deg; base += 4){
        int i = base + sg;
        if (i < deg){
            int s = esrc[off + i];
            acc += ew2[off + i] * h2[(size_t)s * NCLS + col];
        }
    }
    acc += __shfl_xor(acc, 16);
    acc += __shfl_xor(acc, 32);
    if (lane < NCLS) out[(size_t)d * NCLS + lane] = acc + b2[lane];
}

extern "C" void kernel_launch(void* const* d_in, const int* in_sizes, int n_in,
                              void* d_out, int out_size, void* d_ws, size_t ws_size,
                              hipStream_t stream){
    const float* x   = (const float*)d_in[0];
    const int*   ei  = (const int*)d_in[1];
    const int*   src = ei;
    const int*   dst = ei + NEDGE;
    const float* W1  = (const float*)d_in[2];
    const float* as1 = (const float*)d_in[3];
    const float* ad1 = (const float*)d_in[4];
    const float* b1  = (const float*)d_in[5];
    const float* W2  = (const float*)d_in[6];
    const float* as2 = (const float*)d_in[7];
    const float* ad2 = (const float*)d_in[8];
    const float* b2  = (const float*)d_in[9];
    float* out = (float*)d_out;

    char* p = (char*)d_ws;
    auto carve = [&](size_t bytes) -> char* {
        char* r = p; p += (bytes + 255) & ~(size_t)255; return r;
    };
    unsigned short* xb   = (unsigned short*)carve((size_t)N_NODES * F_INK * 2);
    unsigned short* w1t  = (unsigned short*)carve((size_t)HH * F_INK * 2);
    unsigned short* w2t  = (unsigned short*)carve((size_t)HH * NCLS * 2);
    unsigned short* h1b  = (unsigned short*)carve((size_t)N_NODES * HH * 2);
    float* al1s  = (float*)carve((size_t)N_NODES * HEADS * 4);
    float* al1d  = (float*)carve((size_t)N_NODES * HEADS * 4);
    int* counts  = (int*)carve((size_t)N_NODES * 4);
    int* cursor  = (int*)carve((size_t)N_NODES * 4);
    int* offsets = (int*)carve((size_t)(N_NODES + 1) * 4);
    int* blocksums = (int*)carve((size_t)NBLK_SCAN * 4);
    int* blockbase = (int*)carve((size_t)NBLK_SCAN * 4);
    int* esrc    = (int*)carve((size_t)NEDGE * 4);
    float* ew    = (float*)carve((size_t)NEDGE * HEADS * 4);
    float* wselfr= (float*)carve((size_t)N_NODES * HEADS * 4);
    float* dinv  = (float*)carve((size_t)N_NODES * HEADS * 4);
    unsigned short* x2b = (unsigned short*)carve((size_t)N_NODES * HH * 2);
    float* h2    = (float*)carve((size_t)N_NODES * NCLS * 4);
    float* al2s  = (float*)carve((size_t)N_NODES * 4);
    float* al2d  = (float*)carve((size_t)N_NODES * 4);
    float* ew2   = (float*)carve((size_t)NEDGE * 4);
    float* wself2= (float*)carve((size_t)N_NODES * 4);
    if ((size_t)(p - (char*)d_ws) > ws_size) return;  // workspace too small

    hipMemsetAsync(counts, 0, N_NODES * 4, stream);
    hipMemsetAsync(cursor, 0, N_NODES * 4, stream);

    cvt_f32_bf16<<<2048, 256, 0, stream>>>(x, xb, N_NODES * F_INK / 4);
    cvt_w1t<<<(F_INK * HH + 255) / 256, 256, 0, stream>>>(W1, w1t);
    cvt_w2t<<<(HH * NCLS + 255) / 256, 256, 0, stream>>>(W2, w2t);
    count_edges<<<(NEDGE + 255) / 256, 256, 0, stream>>>(dst, counts);
    scan_part<<<NBLK_SCAN, 256, 0, stream>>>(counts, blocksums);
    scan_top<<<1, 256, 0, stream>>>(blocksums, blockbase, offsets);
    scan_write<<<NBLK_SCAN, 256, 0, stream>>>(counts, blockbase, offsets);
    scatter_edges<<<(NEDGE + 255) / 256, 256, 0, stream>>>(src, dst, offsets, cursor, esrc);
    gemm1<<<8 * 128, 256, 0, stream>>>(xb, w1t, h1b);
    attn1_dots<<<(N_NODES + 3) / 4, 256, 0, stream>>>(h1b, as1, ad1, al1s, al1d);
    softmax1<<<(N_NODES + 3) / 4, 256, 0, stream>>>(al1s, al1d, offsets, esrc, ew, wselfr, dinv);
    agg1<<<(N_NODES + 3) / 4, 256, 0, stream>>>(h1b, ew, wselfr, dinv, offsets, esrc, b1, x2b);
    gemm2<<<(N_NODES / 16 + 3) / 4, 256, 0, stream>>>(x2b, w2t, as2, ad2, h2, al2s, al2d);
    softmax2<<<(N_NODES + 3) / 4, 256, 0, stream>>>(al2s, al2d, offsets, esrc, ew2, wself2);
    agg2<<<(N_NODES + 3) / 4, 256, 0, stream>>>(h2, ew2, wself2, offsets, esrc, b2, out);
}